// Round 1
// 411.612 us; speedup vs baseline: 1.0242x; 1.0242x over previous
//
#include <hip/hip_runtime.h>

#define N_NODES 50000
#define N_EDGES 800000
#define D 128
#define NUM_GRAPHS 128

typedef __attribute__((ext_vector_type(8)))  short bfrag8;
typedef __attribute__((ext_vector_type(16))) float f32x16;

__device__ __forceinline__ float4 f4zero() { return make_float4(0.f, 0.f, 0.f, 0.f); }

__device__ __forceinline__ unsigned short f2bf(float f) {
    unsigned u = __float_as_uint(f);
    unsigned r = (u + 0x7fffu + ((u >> 16) & 1u)) >> 16;
    return (unsigned short)r;
}
__device__ __forceinline__ float bf2f(unsigned short b) {
    return __uint_as_float(((unsigned)b) << 16);
}
__device__ __forceinline__ float4 bf2f4(ushort4 u) {
    return make_float4(bf2f(u.x), bf2f(u.y), bf2f(u.z), bf2f(u.w));
}
__device__ __forceinline__ void acc4(float4& a, float4 u) {
    a.x += u.x; a.y += u.y; a.z += u.z; a.w += u.w;
}
// accumulate 8 bf16 packed in a uint4 into 8 fp32 accumulators
// (dword trick: low bf16 = u<<16, high bf16 = u & 0xffff0000 -> 2 instr/elem)
__device__ __forceinline__ void acc8(float* a, uint4 r) {
    a[0] += __uint_as_float(r.x << 16);
    a[1] += __uint_as_float(r.x & 0xffff0000u);
    a[2] += __uint_as_float(r.y << 16);
    a[3] += __uint_as_float(r.y & 0xffff0000u);
    a[4] += __uint_as_float(r.z << 16);
    a[5] += __uint_as_float(r.z & 0xffff0000u);
    a[6] += __uint_as_float(r.w << 16);
    a[7] += __uint_as_float(r.w & 0xffff0000u);
}

// ===========================================================================
// prep: W->Wt (bf16 transposed), x->bf16, zero deg, zero stats (3 layers)
// grid = 512 + 6250 + 196 + 3 = 6961
// ===========================================================================
__global__ __launch_bounds__(256) void prep_kernel(
    const float* __restrict__ W1, const float* __restrict__ W2,
    const float* __restrict__ x, short* __restrict__ Wt,
    ushort4* __restrict__ Hb, int* __restrict__ deg, float* __restrict__ stats)
{
    int b = blockIdx.x, t = threadIdx.x;
    if (b < 512) {
        int idx = b * 256 + t;                 // 131072 = 8*128*128
        int m = idx >> 14, rem = idx & 16383;
        int k = rem >> 7, n = rem & 127;
        const float* W = (m < 4) ? (W1 + (size_t)m * 16384)
                                 : (W2 + (size_t)(m - 4) * 16384);
        Wt[(size_t)m * 16384 + n * 128 + k] = (short)f2bf(W[k * 128 + n]);
    } else if (b < 6762) {
        int i = (b - 512) * 256 + t;           // N*32 = 1,600,000 exactly
        float4 v = ((const float4*)x)[i];
        Hb[i] = make_ushort4(f2bf(v.x), f2bf(v.y), f2bf(v.z), f2bf(v.w));
    } else if (b < 6958) {
        int i = (b - 6762) * 256 + t;
        if (i < N_NODES) deg[i] = 0;
    } else {
        int i = (b - 6958) * 256 + t;          // 768 floats: 3 x (sum||sq)
        stats[i] = 0.f;
    }
}

// ===========================================================================
// CSR build: hist (+ per-edge insertion pos), block scan, fixup, fill
// ===========================================================================
__global__ __launch_bounds__(256) void hist_kernel(
    const int* __restrict__ dst, int* __restrict__ deg,
    int* __restrict__ edge_pos)
{
    int e = blockIdx.x * 256 + threadIdx.x;
    if (e < N_EDGES) edge_pos[e] = atomicAdd(&deg[dst[e]], 1);
}

__global__ __launch_bounds__(256) void scan_block_kernel(
    const int* __restrict__ deg, int* __restrict__ row_ptr,
    int* __restrict__ blockSum)
{
    __shared__ int wsum[4];
    int t = threadIdx.x, b = blockIdx.x;
    int i = b * 256 + t;
    int v = (i < N_NODES) ? deg[i] : 0;
    int lane = t & 63, wid = t >> 6;
    #pragma unroll
    for (int off = 1; off < 64; off <<= 1) {
        int u = __shfl_up(v, off, 64);
        if (lane >= off) v += u;
    }
    if (lane == 63) wsum[wid] = v;
    __syncthreads();
    int add = 0;
    for (int w = 0; w < wid; ++w) add += wsum[w];
    v += add;
    if (i < N_NODES) row_ptr[i + 1] = v;
    if (t == 255) blockSum[b] = v;
}

__global__ __launch_bounds__(256) void scan_fixup_kernel(
    const int* __restrict__ blockSum, int* __restrict__ row_ptr, int nb)
{
    __shared__ int wsum[4];
    __shared__ int sbuf[256];
    int t = threadIdx.x, b = blockIdx.x;
    int v = (t < nb) ? blockSum[t] : 0;
    int lane = t & 63, wid = t >> 6;
    #pragma unroll
    for (int off = 1; off < 64; off <<= 1) {
        int u = __shfl_up(v, off, 64);
        if (lane >= off) v += u;
    }
    if (lane == 63) wsum[wid] = v;
    __syncthreads();
    int add = 0;
    for (int w = 0; w < wid; ++w) add += wsum[w];
    sbuf[t] = v + add;
    __syncthreads();
    if (b == 0 && t == 0) row_ptr[0] = 0;
    if (b > 0) {
        int off = sbuf[b - 1];
        int i = b * 256 + t;
        if (i < N_NODES) row_ptr[i + 1] += off;
    }
}

__global__ __launch_bounds__(256) void fill_kernel(
    const int* __restrict__ src, const int* __restrict__ dst,
    const int* __restrict__ row_ptr, const int* __restrict__ edge_pos,
    int* __restrict__ csr_src)
{
    int e = blockIdx.x * 256 + threadIdx.x;
    if (e >= N_EDGES) return;
    csr_src[row_ptr[dst[e]] + edge_pos[e]] = src[e];
}

// ===========================================================================
// bnapply: H <- relu(bn(H)) in-place, once per layer (hoisted out of gather).
// 800000 uint4 (= 50000 rows x 16), grid 3125 x 256 exact.
// ===========================================================================
__global__ __launch_bounds__(256) void bnapply_kernel(
    uint4* __restrict__ H, const float* __restrict__ stats,
    const float* __restrict__ gamma, const float* __restrict__ beta)
{
    __shared__ float sa[128], sb[128];
    int tid = threadIdx.x;
    if (tid < 128) {
        const float invN = 1.0f / (float)N_NODES;
        float m = stats[tid] * invN;
        float a = gamma[tid] * rsqrtf(stats[128 + tid] * invN - m * m + 1e-5f);
        sa[tid] = a;
        sb[tid] = beta[tid] - m * a;
    }
    __syncthreads();
    int id = blockIdx.x * 256 + tid;          // [0, 800000)
    int c0 = (id & 15) * 8;
    uint4 u = H[id];
    float lo, hi;
    lo = fmaxf(sa[c0 + 0] * __uint_as_float(u.x << 16)          + sb[c0 + 0], 0.f);
    hi = fmaxf(sa[c0 + 1] * __uint_as_float(u.x & 0xffff0000u) + sb[c0 + 1], 0.f);
    u.x = (unsigned)f2bf(lo) | ((unsigned)f2bf(hi) << 16);
    lo = fmaxf(sa[c0 + 2] * __uint_as_float(u.y << 16)          + sb[c0 + 2], 0.f);
    hi = fmaxf(sa[c0 + 3] * __uint_as_float(u.y & 0xffff0000u) + sb[c0 + 3], 0.f);
    u.y = (unsigned)f2bf(lo) | ((unsigned)f2bf(hi) << 16);
    lo = fmaxf(sa[c0 + 4] * __uint_as_float(u.z << 16)          + sb[c0 + 4], 0.f);
    hi = fmaxf(sa[c0 + 5] * __uint_as_float(u.z & 0xffff0000u) + sb[c0 + 5], 0.f);
    u.z = (unsigned)f2bf(lo) | ((unsigned)f2bf(hi) << 16);
    lo = fmaxf(sa[c0 + 6] * __uint_as_float(u.w << 16)          + sb[c0 + 6], 0.f);
    hi = fmaxf(sa[c0 + 7] * __uint_as_float(u.w & 0xffff0000u) + sb[c0 + 7], 0.f);
    u.w = (unsigned)f2bf(lo) | ((unsigned)f2bf(hi) << 16);
    H[id] = u;
}

// ===========================================================================
// Gather (pure sum, BN pre-applied): A[n] = bf16((1+eps)*H[n] + sum H[j]).
// 16 lanes per node, uint4 (16B) per lane, 8-deep unroll, fp32 accumulation.
// grid 3125 x 256 (exactly 50000 nodes).
// ===========================================================================
__global__ __launch_bounds__(256) void gather_kernel(
    const uint4* __restrict__ H, const int* __restrict__ row_ptr,
    const int* __restrict__ csr_src, const float* __restrict__ epsp,
    uint4* __restrict__ A)
{
    int node = blockIdx.x * 16 + (threadIdx.x >> 4);
    int lane = threadIdx.x & 15;
    float eps1 = 1.0f + *epsp;
    int beg = row_ptr[node], end = row_ptr[node + 1];

    uint4 hv = H[node * 16 + lane];
    float acc[8];
    acc[0] = eps1 * __uint_as_float(hv.x << 16);
    acc[1] = eps1 * __uint_as_float(hv.x & 0xffff0000u);
    acc[2] = eps1 * __uint_as_float(hv.y << 16);
    acc[3] = eps1 * __uint_as_float(hv.y & 0xffff0000u);
    acc[4] = eps1 * __uint_as_float(hv.z << 16);
    acc[5] = eps1 * __uint_as_float(hv.z & 0xffff0000u);
    acc[6] = eps1 * __uint_as_float(hv.w << 16);
    acc[7] = eps1 * __uint_as_float(hv.w & 0xffff0000u);

    for (int base = beg; base < end; base += 16) {
        int idx = (base + lane < end) ? csr_src[base + lane] : 0;
        int cnt = min(16, end - base);
        int j = 0;
        for (; j + 8 <= cnt; j += 8) {
            int s0 = __shfl(idx, j + 0, 16), s1 = __shfl(idx, j + 1, 16);
            int s2 = __shfl(idx, j + 2, 16), s3 = __shfl(idx, j + 3, 16);
            int s4 = __shfl(idx, j + 4, 16), s5 = __shfl(idx, j + 5, 16);
            int s6 = __shfl(idx, j + 6, 16), s7 = __shfl(idx, j + 7, 16);
            uint4 u0 = H[s0 * 16 + lane];
            uint4 u1 = H[s1 * 16 + lane];
            uint4 u2 = H[s2 * 16 + lane];
            uint4 u3 = H[s3 * 16 + lane];
            uint4 u4 = H[s4 * 16 + lane];
            uint4 u5 = H[s5 * 16 + lane];
            uint4 u6 = H[s6 * 16 + lane];
            uint4 u7 = H[s7 * 16 + lane];
            acc8(acc, u0); acc8(acc, u1); acc8(acc, u2); acc8(acc, u3);
            acc8(acc, u4); acc8(acc, u5); acc8(acc, u6); acc8(acc, u7);
        }
        for (; j + 4 <= cnt; j += 4) {
            int s0 = __shfl(idx, j + 0, 16), s1 = __shfl(idx, j + 1, 16);
            int s2 = __shfl(idx, j + 2, 16), s3 = __shfl(idx, j + 3, 16);
            uint4 u0 = H[s0 * 16 + lane];
            uint4 u1 = H[s1 * 16 + lane];
            uint4 u2 = H[s2 * 16 + lane];
            uint4 u3 = H[s3 * 16 + lane];
            acc8(acc, u0); acc8(acc, u1); acc8(acc, u2); acc8(acc, u3);
        }
        for (; j < cnt; ++j) {
            int s = __shfl(idx, j, 16);
            uint4 u = H[s * 16 + lane];
            acc8(acc, u);
        }
    }
    uint4 o;
    o.x = (unsigned)f2bf(acc[0]) | ((unsigned)f2bf(acc[1]) << 16);
    o.y = (unsigned)f2bf(acc[2]) | ((unsigned)f2bf(acc[3]) << 16);
    o.z = (unsigned)f2bf(acc[4]) | ((unsigned)f2bf(acc[5]) << 16);
    o.w = (unsigned)f2bf(acc[6]) | ((unsigned)f2bf(acc[7]) << 16);
    A[node * 16 + lane] = o;
}

// ===========================================================================
// Fused MLP:  z2 = (relu(A @ W1 + b1)) @ W2 + b2, bf16 MFMA 32x32x16.
// Block = 256 thr = 4 waves over a 64-row tile: wave wv -> row-group
// rg=wv&1 (rows rg*32..+32), col-half ch=wv>>1 (cols ch*64..+64).
// W1/W2 staged to LDS (32KB, reused) with XOR-chunk swizzle; z1/z2
// round-trip through zlds[rg] (32x128 bf16, shared by the 2 ch-waves).
// ===========================================================================
__global__ __launch_bounds__(256, 3) void mlp_fused_kernel(
    const ushort* __restrict__ A,
    const short* __restrict__ Wt1,
    const short* __restrict__ Wt2,
    const float* __restrict__ bias1,
    const float* __restrict__ bias2,
    ushort* __restrict__ Hout,
    float* __restrict__ statsSum,
    float* __restrict__ statsSq,
    int M)
{
    __shared__ __align__(16) short Wlds[128 * 128];   // 32 KB
    __shared__ __align__(16) short zlds[2][32 * 128]; // 16 KB
    __shared__ float ssum[128];
    __shared__ float ssq[128];

    const int tid  = threadIdx.x;
    const int wv   = tid >> 6;
    const int lane = tid & 63;
    const int half = lane >> 5;
    const int ln   = lane & 31;
    const int rg   = wv & 1;
    const int ch   = wv >> 1;
    const int row0 = blockIdx.x * 64 + rg * 32;
    const bool doStats = (statsSum != nullptr);
    if (doStats && tid < 128) { ssum[tid] = 0.f; ssq[tid] = 0.f; }

    short* zw = &zlds[rg][0];

    // ---- stage W1 -> Wlds (chunk c of row n at c^(n&15)) ----
    {
        const int4* Wg = (const int4*)Wt1;
        int4* Wl = (int4*)Wlds;
        #pragma unroll
        for (int i = 0; i < 8; ++i) {
            int id = i * 256 + tid;            // 2048 int4
            int n = id >> 4, c = id & 15;
            Wl[n * 16 + (c ^ (n & 15))] = Wg[id];
        }
    }
    __syncthreads();   // S0: W1 staged, ssum init

    // ---- GEMM1: z1 = relu(A@W1 + b1) -> zlds[rg] ----
    {
        f32x16 acc[2];
        #pragma unroll
        for (int ci = 0; ci < 2; ++ci)
            #pragma unroll
            for (int r = 0; r < 16; ++r) acc[ci][r] = 0.f;

        bfrag8 af[8];
        int rowc = min(row0 + ln, M - 1);
        const ushort* ap = A + (size_t)rowc * 128 + half * 8;
        #pragma unroll
        for (int kk = 0; kk < 8; ++kk)
            af[kk] = *(const bfrag8*)(ap + kk * 16);

        #pragma unroll
        for (int kk = 0; kk < 8; ++kk) {
            #pragma unroll
            for (int ci = 0; ci < 2; ++ci) {
                int n = (ch * 2 + ci) * 32 + ln;
                int c = kk * 2 + half;
                bfrag8 bf = *(const bfrag8*)(Wlds + n * 128 + ((c ^ (n & 15)) << 3));
                acc[ci] = __builtin_amdgcn_mfma_f32_32x32x16_bf16(
                    af[kk], bf, acc[ci], 0, 0, 0);
            }
        }
        #pragma unroll
        for (int ci = 0; ci < 2; ++ci) {
            int col = (ch * 2 + ci) * 32 + ln;
            int cc = col >> 3, co = col & 7;
            float bv = bias1[col];
            #pragma unroll
            for (int r = 0; r < 16; ++r) {
                int rloc = (r & 3) + 8 * (r >> 2) + 4 * half;
                float v = fmaxf(acc[ci][r] + bv, 0.f);
                zw[rloc * 128 + ((cc ^ (rloc & 15)) << 3) + co] = (short)f2bf(v);
            }
        }
    }
    __syncthreads();   // S1: z1 complete, G1 Wlds reads done

    // ---- stage W2 -> Wlds; preload af2 from zlds[rg] ----
    bfrag8 af2[8];
    #pragma unroll
    for (int kk = 0; kk < 8; ++kk) {
        int c = kk * 2 + half;
        af2[kk] = *(const bfrag8*)(zw + ln * 128 + ((c ^ (ln & 15)) << 3));
    }
    {
        const int4* Wg = (const int4*)Wt2;
        int4* Wl = (int4*)Wlds;
        #pragma unroll
        for (int i = 0; i < 8; ++i) {
            int id = i * 256 + tid;
            int n = id >> 4, c = id & 15;
            Wl[n * 16 + (c ^ (n & 15))] = Wg[id];
        }
    }
    __syncthreads();   // S2: W2 staged, all af2 preloads done

    // ---- GEMM2: z2 = z1 @ W2 + b2 -> zlds[rg]; stats on fp32 values ----
    {
        f32x16 acc[2];
        #pragma unroll
        for (int ci = 0; ci < 2; ++ci)
            #pragma unroll
            for (int r = 0; r < 16; ++r) acc[ci][r] = 0.f;

        #pragma unroll
        for (int kk = 0; kk < 8; ++kk) {
            #pragma unroll
            for (int ci = 0; ci < 2; ++ci) {
                int n = (ch * 2 + ci) * 32 + ln;
                int c = kk * 2 + half;
                bfrag8 bf = *(const bfrag8*)(Wlds + n * 128 + ((c ^ (n & 15)) << 3));
                acc[ci] = __builtin_amdgcn_mfma_f32_32x32x16_bf16(
                    af2[kk], bf, acc[ci], 0, 0, 0);
            }
        }
        #pragma unroll
        for (int ci = 0; ci < 2; ++ci) {
            int col = (ch * 2 + ci) * 32 + ln;
            int cc = col >> 3, co = col & 7;
            float bv = bias2[col];
            float s = 0.f, sq = 0.f;
            #pragma unroll
            for (int r = 0; r < 16; ++r) {
                int rloc = (r & 3) + 8 * (r >> 2) + 4 * half;
                float v = acc[ci][r] + bv;
                zw[rloc * 128 + ((cc ^ (rloc & 15)) << 3) + co] = (short)f2bf(v);
                if (row0 + rloc < M) { s += v; sq += v * v; }
            }
            if (doStats) {
                s  += __shfl_xor(s, 32);
                sq += __shfl_xor(sq, 32);
                if (half == 0) {
                    atomicAdd(&ssum[col], s);
                    atomicAdd(&ssq[col], sq);
                }
            }
        }
    }
    __syncthreads();   // S3: z2 complete, ssum atomics done

    // ---- coalesced store: zlds -> Hout (64 rows x 16 int4) ----
    {
        int4* Ho = (int4*)Hout;
        #pragma unroll
        for (int i = 0; i < 4; ++i) {
            int id = i * 256 + tid;            // 1024 int4
            int r = id >> 4, c = id & 15;
            int rl = r & 31;
            int grow = blockIdx.x * 64 + r;
            if (grow < M)
                Ho[(size_t)grow * 16 + c] =
                    ((const int4*)&zlds[r >> 5][0])[rl * 16 + (c ^ (rl & 15))];
        }
    }
    if (doStats && tid < 128) {
        atomicAdd(&statsSum[tid], ssum[tid]);
        atomicAdd(&statsSq[tid],  ssq[tid]);
    }
}

// ===========================================================================
// global_add_pool: batch sorted -> run-length accumulate.
// ===========================================================================
__global__ __launch_bounds__(256) void pool_kernel(
    const ushort4* __restrict__ H, const int* __restrict__ batch,
    float* __restrict__ out)
{
    int c4 = threadIdx.x & 31;
    int nl = threadIdx.x >> 5;
    int node0 = blockIdx.x * 256;
    float4 acc = f4zero();
    int gcur = -1;
    for (int i = nl; i < 256; i += 8) {
        int n = node0 + i;
        if (n >= N_NODES) break;
        int g = batch[n];
        if (g != gcur) {
            if (gcur >= 0) {
                float* o = out + gcur * D + c4 * 4;
                atomicAdd(o + 0, acc.x); atomicAdd(o + 1, acc.y);
                atomicAdd(o + 2, acc.z); atomicAdd(o + 3, acc.w);
            }
            gcur = g;
            acc = f4zero();
        }
        float4 v = bf2f4(H[n * 32 + c4]);
        acc4(acc, v);
    }
    if (gcur >= 0) {
        float* o = out + gcur * D + c4 * 4;
        atomicAdd(o + 0, acc.x); atomicAdd(o + 1, acc.y);
        atomicAdd(o + 2, acc.z); atomicAdd(o + 3, acc.w);
    }
}

extern "C" void kernel_launch(void* const* d_in, const int* in_sizes, int n_in,
                              void* d_out, int out_size, void* d_ws, size_t ws_size,
                              hipStream_t stream)
{
    const float* x     = (const float*)d_in[0];
    const int*   ei    = (const int*)d_in[1];
    const int*   batch = (const int*)d_in[2];
    const float* W1    = (const float*)d_in[3];
    const float* b1    = (const float*)d_in[4];
    const float* W2    = (const float*)d_in[5];
    const float* b2    = (const float*)d_in[6];
    const float* eps   = (const float*)d_in[7];
    const float* gamma = (const float*)d_in[8];
    const float* beta  = (const float*)d_in[9];
    float* out = (float*)d_out;

    // ---- workspace layout ----
    unsigned short* Hb  = (unsigned short*)d_ws;          // [N,128] bf16
    unsigned short* Abf = Hb + (size_t)N_NODES * D;       // [N,128] bf16
    float* stats    = (float*)(Abf + (size_t)N_NODES * D);// [3][256] sum||sq
    int*   deg      = (int*)(stats + 3 * 256);            // [N]
    int*   row_ptr  = deg + N_NODES;                      // [N+1]
    int*   blockSum = row_ptr + N_NODES + 1;              // [256]
    int*   edge_pos = blockSum + 256;                     // [E]
    int*   csr_src  = edge_pos + N_EDGES;                 // [E]
    short* Wt       = (short*)(csr_src + N_EDGES);        // [8][128][128]

    const int* src = ei;
    const int* dst = ei + N_EDGES;

    const int edgeBlocks   = (N_EDGES + 255) / 256;      // 3125
    const int scanBlocks   = (N_NODES + 255) / 256;      // 196
    const int gatherBlocks = (N_NODES + 15) / 16;        // 3125
    const int bnBlocks     = (N_NODES * 16) / 256;       // 3125 exact
    const int gemmBlocks   = (N_NODES + 63) / 64;        // 782

    prep_kernel<<<6961, 256, 0, stream>>>(W1, W2, x, Wt, (ushort4*)Hb,
                                          deg, stats);
    hist_kernel<<<edgeBlocks, 256, 0, stream>>>(dst, deg, edge_pos);
    scan_block_kernel<<<scanBlocks, 256, 0, stream>>>(deg, row_ptr, blockSum);
    scan_fixup_kernel<<<scanBlocks, 256, 0, stream>>>(blockSum, row_ptr, scanBlocks);
    fill_kernel<<<edgeBlocks, 256, 0, stream>>>(src, dst, row_ptr, edge_pos, csr_src);

    for (int layer = 0; layer < 4; ++layer) {
        const bool bn = (layer < 3);
        if (layer > 0) {
            bnapply_kernel<<<bnBlocks, 256, 0, stream>>>(
                (uint4*)Hb, stats + (size_t)(layer - 1) * 256,
                gamma + (size_t)(layer - 1) * D, beta + (size_t)(layer - 1) * D);
        }
        gather_kernel<<<gatherBlocks, 256, 0, stream>>>(
            (const uint4*)Hb, row_ptr, csr_src, eps + layer, (uint4*)Abf);
        mlp_fused_kernel<<<gemmBlocks, 256, 0, stream>>>(
            Abf, Wt + (size_t)layer * 16384, Wt + (size_t)(4 + layer) * 16384,
            b1 + (size_t)layer * D, b2 + (size_t)layer * D, Hb,
            bn ? stats + layer * 256 : nullptr,
            bn ? stats + layer * 256 + 128 : nullptr, N_NODES);
    }

    hipMemsetAsync(out, 0, (size_t)NUM_GRAPHS * D * sizeof(float), stream);
    pool_kernel<<<scanBlocks, 256, 0, stream>>>(
        (const ushort4*)Hb, batch, out);
}

// Round 2
// 389.374 us; speedup vs baseline: 1.0827x; 1.0571x over previous
//
#include <hip/hip_runtime.h>

#define N_NODES 50000
#define N_EDGES 800000
#define D 128
#define NUM_GRAPHS 128

typedef __attribute__((ext_vector_type(8)))  short bfrag8;
typedef __attribute__((ext_vector_type(16))) float f32x16;

__device__ __forceinline__ float4 f4zero() { return make_float4(0.f, 0.f, 0.f, 0.f); }

__device__ __forceinline__ unsigned short f2bf(float f) {
    unsigned u = __float_as_uint(f);
    unsigned r = (u + 0x7fffu + ((u >> 16) & 1u)) >> 16;
    return (unsigned short)r;
}
__device__ __forceinline__ float bf2f(unsigned short b) {
    return __uint_as_float(((unsigned)b) << 16);
}
__device__ __forceinline__ void acc8(float* a, uint4 r) {
    a[0] += __uint_as_float(r.x << 16);
    a[1] += __uint_as_float(r.x & 0xffff0000u);
    a[2] += __uint_as_float(r.y << 16);
    a[3] += __uint_as_float(r.y & 0xffff0000u);
    a[4] += __uint_as_float(r.z << 16);
    a[5] += __uint_as_float(r.z & 0xffff0000u);
    a[6] += __uint_as_float(r.w << 16);
    a[7] += __uint_as_float(r.w & 0xffff0000u);
}

// ===========================================================================
// prep: W->Wt (bf16 transposed), x->bf16, zero deg, zero stats, zero dummy row
// grid = 512 + 6250 + 196 + 3 + 1 = 6962
// ===========================================================================
__global__ __launch_bounds__(256) void prep_kernel(
    const float* __restrict__ W1, const float* __restrict__ W2,
    const float* __restrict__ x, short* __restrict__ Wt,
    ushort4* __restrict__ Hb, int* __restrict__ deg, float* __restrict__ stats)
{
    int b = blockIdx.x, t = threadIdx.x;
    if (b < 512) {
        int idx = b * 256 + t;                 // 131072 = 8*128*128
        int m = idx >> 14, rem = idx & 16383;
        int k = rem >> 7, n = rem & 127;
        const float* W = (m < 4) ? (W1 + (size_t)m * 16384)
                                 : (W2 + (size_t)(m - 4) * 16384);
        Wt[(size_t)m * 16384 + n * 128 + k] = (short)f2bf(W[k * 128 + n]);
    } else if (b < 6762) {
        int i = (b - 512) * 256 + t;           // N*32 = 1,600,000 exactly
        float4 v = ((const float4*)x)[i];
        Hb[i] = make_ushort4(f2bf(v.x), f2bf(v.y), f2bf(v.z), f2bf(v.w));
    } else if (b < 6958) {
        int i = (b - 6762) * 256 + t;
        if (i < N_NODES) deg[i] = 0;
    } else if (b < 6961) {
        int i = (b - 6958) * 256 + t;          // 768 floats: 3 x (sum||sq)
        stats[i] = 0.f;
    } else {
        // zero dummy row N_NODES (64 dwords = 256 B)
        if (t < 64) ((unsigned*)Hb)[(size_t)N_NODES * 64 + t] = 0u;
    }
}

// ===========================================================================
// CSR build (padded to multiple of 8 per row, ushort entries)
// ===========================================================================
__global__ __launch_bounds__(256) void hist_kernel(
    const int* __restrict__ dst, int* __restrict__ deg,
    unsigned short* __restrict__ edge_pos)
{
    int e = blockIdx.x * 256 + threadIdx.x;
    if (e < N_EDGES) edge_pos[e] = (unsigned short)atomicAdd(&deg[dst[e]], 1);
}

__global__ __launch_bounds__(256) void scan_block_kernel(
    const int* __restrict__ deg, int* __restrict__ row_ptr,
    int* __restrict__ blockSum)
{
    __shared__ int wsum[4];
    int t = threadIdx.x, b = blockIdx.x;
    int i = b * 256 + t;
    int v = (i < N_NODES) ? ((deg[i] + 7) & ~7) : 0;   // padded degree
    int lane = t & 63, wid = t >> 6;
    #pragma unroll
    for (int off = 1; off < 64; off <<= 1) {
        int u = __shfl_up(v, off, 64);
        if (lane >= off) v += u;
    }
    if (lane == 63) wsum[wid] = v;
    __syncthreads();
    int add = 0;
    for (int w = 0; w < wid; ++w) add += wsum[w];
    v += add;
    if (i < N_NODES) row_ptr[i + 1] = v;
    if (t == 255) blockSum[b] = v;
}

__global__ __launch_bounds__(256) void scan_fixup_kernel(
    const int* __restrict__ blockSum, int* __restrict__ row_ptr, int nb)
{
    __shared__ int wsum[4];
    __shared__ int sbuf[256];
    int t = threadIdx.x, b = blockIdx.x;
    int v = (t < nb) ? blockSum[t] : 0;
    int lane = t & 63, wid = t >> 6;
    #pragma unroll
    for (int off = 1; off < 64; off <<= 1) {
        int u = __shfl_up(v, off, 64);
        if (lane >= off) v += u;
    }
    if (lane == 63) wsum[wid] = v;
    __syncthreads();
    int add = 0;
    for (int w = 0; w < wid; ++w) add += wsum[w];
    sbuf[t] = v + add;
    __syncthreads();
    if (b == 0 && t == 0) row_ptr[0] = 0;
    if (b > 0) {
        int off = sbuf[b - 1];
        int i = b * 256 + t;
        if (i < N_NODES) row_ptr[i + 1] += off;
    }
}

// edge fill (blocks [0,3125)) + pad-slot fill with dummy node (blocks >= 3125)
__global__ __launch_bounds__(256) void fill_kernel(
    const int* __restrict__ src, const int* __restrict__ dst,
    const int* __restrict__ row_ptr, const unsigned short* __restrict__ edge_pos,
    const int* __restrict__ deg, unsigned short* __restrict__ csr_src)
{
    int b = blockIdx.x, t = threadIdx.x;
    if (b < 3125) {
        int e = b * 256 + t;
        if (e < N_EDGES)
            csr_src[row_ptr[dst[e]] + (int)edge_pos[e]] = (unsigned short)src[e];
    } else {
        int n = (b - 3125) * 256 + t;
        if (n < N_NODES) {
            int e0 = row_ptr[n] + deg[n];
            int e1 = row_ptr[n + 1];
            for (int j = e0; j < e1; ++j)
                csr_src[j] = (unsigned short)N_NODES;
        }
    }
}

// ===========================================================================
// bnapply: H <- relu(bn(H)) in-place, once per layer.
// ===========================================================================
__global__ __launch_bounds__(256) void bnapply_kernel(
    uint4* __restrict__ H, const float* __restrict__ stats,
    const float* __restrict__ gamma, const float* __restrict__ beta)
{
    __shared__ float sa[128], sb[128];
    int tid = threadIdx.x;
    if (tid < 128) {
        const float invN = 1.0f / (float)N_NODES;
        float m = stats[tid] * invN;
        float a = gamma[tid] * rsqrtf(stats[128 + tid] * invN - m * m + 1e-5f);
        sa[tid] = a;
        sb[tid] = beta[tid] - m * a;
    }
    __syncthreads();
    int id = blockIdx.x * 256 + tid;          // [0, 800000)
    int c0 = (id & 15) * 8;
    uint4 u = H[id];
    float lo, hi;
    lo = fmaxf(sa[c0 + 0] * __uint_as_float(u.x << 16)          + sb[c0 + 0], 0.f);
    hi = fmaxf(sa[c0 + 1] * __uint_as_float(u.x & 0xffff0000u) + sb[c0 + 1], 0.f);
    u.x = (unsigned)f2bf(lo) | ((unsigned)f2bf(hi) << 16);
    lo = fmaxf(sa[c0 + 2] * __uint_as_float(u.y << 16)          + sb[c0 + 2], 0.f);
    hi = fmaxf(sa[c0 + 3] * __uint_as_float(u.y & 0xffff0000u) + sb[c0 + 3], 0.f);
    u.y = (unsigned)f2bf(lo) | ((unsigned)f2bf(hi) << 16);
    lo = fmaxf(sa[c0 + 4] * __uint_as_float(u.z << 16)          + sb[c0 + 4], 0.f);
    hi = fmaxf(sa[c0 + 5] * __uint_as_float(u.z & 0xffff0000u) + sb[c0 + 5], 0.f);
    u.z = (unsigned)f2bf(lo) | ((unsigned)f2bf(hi) << 16);
    lo = fmaxf(sa[c0 + 6] * __uint_as_float(u.w << 16)          + sb[c0 + 6], 0.f);
    hi = fmaxf(sa[c0 + 7] * __uint_as_float(u.w & 0xffff0000u) + sb[c0 + 7], 0.f);
    u.w = (unsigned)f2bf(lo) | ((unsigned)f2bf(hi) << 16);
    H[id] = u;
}

// ===========================================================================
// Gather (padded CSR): A[n] = bf16((1+eps)*H[n] + sum H[j]).
// 16 lanes/node, uint4/lane. Rows padded to x8 with dummy zero row ->
// no tails. Next-chunk index prefetch + 16 loads in flight when cnt>=16.
// ===========================================================================
__global__ __launch_bounds__(256, 4) void gather_kernel(
    const uint4* __restrict__ H, const int* __restrict__ row_ptr,
    const unsigned short* __restrict__ csr, const float* __restrict__ epsp,
    uint4* __restrict__ A)
{
    int node = blockIdx.x * 16 + (threadIdx.x >> 4);
    int lane = threadIdx.x & 15;
    float eps1 = 1.0f + *epsp;
    int beg = row_ptr[node], end = row_ptr[node + 1];

    uint4 hv = H[(size_t)node * 16 + lane];
    float acc[8];
    acc[0] = eps1 * __uint_as_float(hv.x << 16);
    acc[1] = eps1 * __uint_as_float(hv.x & 0xffff0000u);
    acc[2] = eps1 * __uint_as_float(hv.y << 16);
    acc[3] = eps1 * __uint_as_float(hv.y & 0xffff0000u);
    acc[4] = eps1 * __uint_as_float(hv.z << 16);
    acc[5] = eps1 * __uint_as_float(hv.z & 0xffff0000u);
    acc[6] = eps1 * __uint_as_float(hv.w << 16);
    acc[7] = eps1 * __uint_as_float(hv.w & 0xffff0000u);

    int base = beg;
    int idx = (int)csr[base + lane];          // +16 slack allocated
    while (base < end) {
        int nb = base + 16;
        int nidx = 0;
        if (nb < end) nidx = (int)csr[nb + lane];
        int cnt = end - base;                 // multiple of 8
        int s0 = __shfl(idx, 0, 16), s1 = __shfl(idx, 1, 16);
        int s2 = __shfl(idx, 2, 16), s3 = __shfl(idx, 3, 16);
        int s4 = __shfl(idx, 4, 16), s5 = __shfl(idx, 5, 16);
        int s6 = __shfl(idx, 6, 16), s7 = __shfl(idx, 7, 16);
        uint4 u0 = H[(size_t)s0 * 16 + lane];
        uint4 u1 = H[(size_t)s1 * 16 + lane];
        uint4 u2 = H[(size_t)s2 * 16 + lane];
        uint4 u3 = H[(size_t)s3 * 16 + lane];
        uint4 u4 = H[(size_t)s4 * 16 + lane];
        uint4 u5 = H[(size_t)s5 * 16 + lane];
        uint4 u6 = H[(size_t)s6 * 16 + lane];
        uint4 u7 = H[(size_t)s7 * 16 + lane];
        if (cnt > 8) {
            int t0 = __shfl(idx,  8, 16), t1 = __shfl(idx,  9, 16);
            int t2 = __shfl(idx, 10, 16), t3 = __shfl(idx, 11, 16);
            int t4 = __shfl(idx, 12, 16), t5 = __shfl(idx, 13, 16);
            int t6 = __shfl(idx, 14, 16), t7 = __shfl(idx, 15, 16);
            uint4 w0 = H[(size_t)t0 * 16 + lane];
            uint4 w1 = H[(size_t)t1 * 16 + lane];
            uint4 w2 = H[(size_t)t2 * 16 + lane];
            uint4 w3 = H[(size_t)t3 * 16 + lane];
            uint4 w4 = H[(size_t)t4 * 16 + lane];
            uint4 w5 = H[(size_t)t5 * 16 + lane];
            uint4 w6 = H[(size_t)t6 * 16 + lane];
            uint4 w7 = H[(size_t)t7 * 16 + lane];
            acc8(acc, u0); acc8(acc, u1); acc8(acc, u2); acc8(acc, u3);
            acc8(acc, u4); acc8(acc, u5); acc8(acc, u6); acc8(acc, u7);
            acc8(acc, w0); acc8(acc, w1); acc8(acc, w2); acc8(acc, w3);
            acc8(acc, w4); acc8(acc, w5); acc8(acc, w6); acc8(acc, w7);
        } else {
            acc8(acc, u0); acc8(acc, u1); acc8(acc, u2); acc8(acc, u3);
            acc8(acc, u4); acc8(acc, u5); acc8(acc, u6); acc8(acc, u7);
        }
        idx = nidx; base = nb;
    }
    uint4 o;
    o.x = (unsigned)f2bf(acc[0]) | ((unsigned)f2bf(acc[1]) << 16);
    o.y = (unsigned)f2bf(acc[2]) | ((unsigned)f2bf(acc[3]) << 16);
    o.z = (unsigned)f2bf(acc[4]) | ((unsigned)f2bf(acc[5]) << 16);
    o.w = (unsigned)f2bf(acc[6]) | ((unsigned)f2bf(acc[7]) << 16);
    A[(size_t)node * 16 + lane] = o;
}

// ===========================================================================
// Fused MLP:  z2 = (relu(A @ W1 + b1)) @ W2 + b2, bf16 MFMA 32x32x16.
// Last layer: global_add_pool fused into epilogue (poolOut != null),
// Hout store skipped.
// ===========================================================================
__global__ __launch_bounds__(256, 3) void mlp_fused_kernel(
    const ushort* __restrict__ A,
    const short* __restrict__ Wt1,
    const short* __restrict__ Wt2,
    const float* __restrict__ bias1,
    const float* __restrict__ bias2,
    ushort* __restrict__ Hout,
    float* __restrict__ statsSum,
    float* __restrict__ statsSq,
    const int* __restrict__ batch,
    float* __restrict__ poolOut,
    int M)
{
    __shared__ __align__(16) short Wlds[128 * 128];   // 32 KB
    __shared__ __align__(16) short zlds[2][32 * 128]; // 16 KB
    __shared__ float ssum[128];
    __shared__ float ssq[128];

    const int tid  = threadIdx.x;
    const int wv   = tid >> 6;
    const int lane = tid & 63;
    const int half = lane >> 5;
    const int ln   = lane & 31;
    const int rg   = wv & 1;
    const int ch   = wv >> 1;
    const int row0 = blockIdx.x * 64 + rg * 32;
    const bool doStats = (statsSum != nullptr);
    if (doStats && tid < 128) { ssum[tid] = 0.f; ssq[tid] = 0.f; }

    short* zw = &zlds[rg][0];

    // ---- stage W1 -> Wlds (chunk c of row n at c^(n&15)) ----
    {
        const int4* Wg = (const int4*)Wt1;
        int4* Wl = (int4*)Wlds;
        #pragma unroll
        for (int i = 0; i < 8; ++i) {
            int id = i * 256 + tid;            // 2048 int4
            int n = id >> 4, c = id & 15;
            Wl[n * 16 + (c ^ (n & 15))] = Wg[id];
        }
    }
    __syncthreads();   // S0: W1 staged, ssum init

    // ---- GEMM1: z1 = relu(A@W1 + b1) -> zlds[rg] ----
    {
        f32x16 acc[2];
        #pragma unroll
        for (int ci = 0; ci < 2; ++ci)
            #pragma unroll
            for (int r = 0; r < 16; ++r) acc[ci][r] = 0.f;

        bfrag8 af[8];
        int rowc = min(row0 + ln, M - 1);
        const ushort* ap = A + (size_t)rowc * 128 + half * 8;
        #pragma unroll
        for (int kk = 0; kk < 8; ++kk)
            af[kk] = *(const bfrag8*)(ap + kk * 16);

        #pragma unroll
        for (int kk = 0; kk < 8; ++kk) {
            #pragma unroll
            for (int ci = 0; ci < 2; ++ci) {
                int n = (ch * 2 + ci) * 32 + ln;
                int c = kk * 2 + half;
                bfrag8 bf = *(const bfrag8*)(Wlds + n * 128 + ((c ^ (n & 15)) << 3));
                acc[ci] = __builtin_amdgcn_mfma_f32_32x32x16_bf16(
                    af[kk], bf, acc[ci], 0, 0, 0);
            }
        }
        #pragma unroll
        for (int ci = 0; ci < 2; ++ci) {
            int col = (ch * 2 + ci) * 32 + ln;
            int cc = col >> 3, co = col & 7;
            float bv = bias1[col];
            #pragma unroll
            for (int r = 0; r < 16; ++r) {
                int rloc = (r & 3) + 8 * (r >> 2) + 4 * half;
                float v = fmaxf(acc[ci][r] + bv, 0.f);
                zw[rloc * 128 + ((cc ^ (rloc & 15)) << 3) + co] = (short)f2bf(v);
            }
        }
    }
    __syncthreads();   // S1: z1 complete, G1 Wlds reads done

    // ---- stage W2 -> Wlds; preload af2 from zlds[rg] ----
    bfrag8 af2[8];
    #pragma unroll
    for (int kk = 0; kk < 8; ++kk) {
        int c = kk * 2 + half;
        af2[kk] = *(const bfrag8*)(zw + ln * 128 + ((c ^ (ln & 15)) << 3));
    }
    {
        const int4* Wg = (const int4*)Wt2;
        int4* Wl = (int4*)Wlds;
        #pragma unroll
        for (int i = 0; i < 8; ++i) {
            int id = i * 256 + tid;
            int n = id >> 4, c = id & 15;
            Wl[n * 16 + (c ^ (n & 15))] = Wg[id];
        }
    }
    __syncthreads();   // S2: W2 staged, all af2 preloads done

    // ---- GEMM2: z2 = z1 @ W2 + b2 -> zlds[rg]; stats on fp32 values ----
    {
        f32x16 acc[2];
        #pragma unroll
        for (int ci = 0; ci < 2; ++ci)
            #pragma unroll
            for (int r = 0; r < 16; ++r) acc[ci][r] = 0.f;

        #pragma unroll
        for (int kk = 0; kk < 8; ++kk) {
            #pragma unroll
            for (int ci = 0; ci < 2; ++ci) {
                int n = (ch * 2 + ci) * 32 + ln;
                int c = kk * 2 + half;
                bfrag8 bf = *(const bfrag8*)(Wlds + n * 128 + ((c ^ (n & 15)) << 3));
                acc[ci] = __builtin_amdgcn_mfma_f32_32x32x16_bf16(
                    af2[kk], bf, acc[ci], 0, 0, 0);
            }
        }
        #pragma unroll
        for (int ci = 0; ci < 2; ++ci) {
            int col = (ch * 2 + ci) * 32 + ln;
            int cc = col >> 3, co = col & 7;
            float bv = bias2[col];
            float s = 0.f, sq = 0.f;
            #pragma unroll
            for (int r = 0; r < 16; ++r) {
                int rloc = (r & 3) + 8 * (r >> 2) + 4 * half;
                float v = acc[ci][r] + bv;
                zw[rloc * 128 + ((cc ^ (rloc & 15)) << 3) + co] = (short)f2bf(v);
                if (row0 + rloc < M) { s += v; sq += v * v; }
            }
            if (doStats) {
                s  += __shfl_xor(s, 32);
                sq += __shfl_xor(sq, 32);
                if (half == 0) {
                    atomicAdd(&ssum[col], s);
                    atomicAdd(&ssq[col], sq);
                }
            }
        }
    }
    __syncthreads();   // S3: z2 complete, ssum atomics done

    if (poolOut == nullptr) {
        // ---- coalesced store: zlds -> Hout (64 rows x 16 int4) ----
        int4* Ho = (int4*)Hout;
        #pragma unroll
        for (int i = 0; i < 4; ++i) {
            int id = i * 256 + tid;            // 1024 int4
            int r = id >> 4, c = id & 15;
            int rl = r & 31;
            int grow = blockIdx.x * 64 + r;
            if (grow < M)
                Ho[(size_t)grow * 16 + c] =
                    ((const int4*)&zlds[r >> 5][0])[rl * 16 + (c ^ (rl & 15))];
        }
    } else {
        // ---- fused global_add_pool: sum rows by (sorted) batch id ----
        int c4 = tid & 31;                     // column quad c4*4..+3
        int rl8 = tid >> 5;                    // 8 row-lanes
        int cc = c4 >> 1, co = (c4 & 1) * 4;
        float4 ap = f4zero();
        int gcur = -1;
        for (int i = rl8; i < 64; i += 8) {
            int grow = blockIdx.x * 64 + i;
            if (grow >= M) break;
            int g = batch[grow];
            if (g != gcur) {
                if (gcur >= 0) {
                    float* o = poolOut + gcur * D + c4 * 4;
                    atomicAdd(o + 0, ap.x); atomicAdd(o + 1, ap.y);
                    atomicAdd(o + 2, ap.z); atomicAdd(o + 3, ap.w);
                }
                gcur = g; ap = f4zero();
            }
            const short* zr = &zlds[i >> 5][0];
            int rl = i & 31;
            const ushort4 u = *(const ushort4*)
                ((const ushort*)(zr + rl * 128 + ((cc ^ (rl & 15)) << 3) + co));
            ap.x += bf2f(u.x); ap.y += bf2f(u.y);
            ap.z += bf2f(u.z); ap.w += bf2f(u.w);
        }
        if (gcur >= 0) {
            float* o = poolOut + gcur * D + c4 * 4;
            atomicAdd(o + 0, ap.x); atomicAdd(o + 1, ap.y);
            atomicAdd(o + 2, ap.z); atomicAdd(o + 3, ap.w);
        }
    }
    if (doStats && tid < 128) {
        atomicAdd(&statsSum[tid], ssum[tid]);
        atomicAdd(&statsSq[tid],  ssq[tid]);
    }
}

extern "C" void kernel_launch(void* const* d_in, const int* in_sizes, int n_in,
                              void* d_out, int out_size, void* d_ws, size_t ws_size,
                              hipStream_t stream)
{
    const float* x     = (const float*)d_in[0];
    const int*   ei    = (const int*)d_in[1];
    const int*   batch = (const int*)d_in[2];
    const float* W1    = (const float*)d_in[3];
    const float* b1    = (const float*)d_in[4];
    const float* W2    = (const float*)d_in[5];
    const float* b2    = (const float*)d_in[6];
    const float* eps   = (const float*)d_in[7];
    const float* gamma = (const float*)d_in[8];
    const float* beta  = (const float*)d_in[9];
    float* out = (float*)d_out;

    // ---- workspace layout ----
    // Hb has N+1 rows (row N = dummy zero row for CSR padding)
    unsigned short* Hb  = (unsigned short*)d_ws;              // [N+1,128] bf16
    unsigned short* Abf = Hb + (size_t)(N_NODES + 1) * D;     // [N,128] bf16
    float* stats    = (float*)(Abf + (size_t)N_NODES * D);    // [3][256] sum||sq
    int*   deg      = (int*)(stats + 3 * 256);                // [N]
    int*   row_ptr  = deg + N_NODES;                          // [N+1]
    int*   blockSum = row_ptr + N_NODES + 1;                  // [256]
    unsigned short* edge_pos = (unsigned short*)(blockSum + 256);  // [E]
    unsigned short* csr_src  = edge_pos + N_EDGES;            // [E + 7N + 16]
    short* Wt       = (short*)(csr_src + N_EDGES + 7 * N_NODES + 16); // [8][128][128]

    const int* src = ei;
    const int* dst = ei + N_EDGES;

    const int edgeBlocks   = (N_EDGES + 255) / 256;      // 3125
    const int scanBlocks   = (N_NODES + 255) / 256;      // 196
    const int gatherBlocks = (N_NODES + 15) / 16;        // 3125
    const int bnBlocks     = (N_NODES * 16) / 256;       // 3125 exact
    const int gemmBlocks   = (N_NODES + 63) / 64;        // 782

    prep_kernel<<<6962, 256, 0, stream>>>(W1, W2, x, Wt, (ushort4*)Hb,
                                          deg, stats);
    hist_kernel<<<edgeBlocks, 256, 0, stream>>>(dst, deg, edge_pos);
    scan_block_kernel<<<scanBlocks, 256, 0, stream>>>(deg, row_ptr, blockSum);
    scan_fixup_kernel<<<scanBlocks, 256, 0, stream>>>(blockSum, row_ptr, scanBlocks);
    fill_kernel<<<edgeBlocks + scanBlocks, 256, 0, stream>>>(
        src, dst, row_ptr, edge_pos, deg, csr_src);
    hipMemsetAsync(out, 0, (size_t)NUM_GRAPHS * D * sizeof(float), stream);

    for (int layer = 0; layer < 4; ++layer) {
        const bool bn = (layer < 3);
        if (layer > 0) {
            bnapply_kernel<<<bnBlocks, 256, 0, stream>>>(
                (uint4*)Hb, stats + (size_t)(layer - 1) * 256,
                gamma + (size_t)(layer - 1) * D, beta + (size_t)(layer - 1) * D);
        }
        gather_kernel<<<gatherBlocks, 256, 0, stream>>>(
            (const uint4*)Hb, row_ptr, csr_src, eps + layer, (uint4*)Abf);
        mlp_fused_kernel<<<gemmBlocks, 256, 0, stream>>>(
            Abf, Wt + (size_t)layer * 16384, Wt + (size_t)(4 + layer) * 16384,
            b1 + (size_t)layer * D, b2 + (size_t)layer * D, Hb,
            bn ? stats + layer * 256 : nullptr,
            bn ? stats + layer * 256 + 128 : nullptr,
            bn ? nullptr : batch,
            bn ? nullptr : out, N_NODES);
    }
}

// Round 3
// 360.944 us; speedup vs baseline: 1.1680x; 1.0788x over previous
//
#include <hip/hip_runtime.h>

#define N_NODES 50000
#define N_EDGES 800000
#define D 128
#define NUM_GRAPHS 128

typedef __attribute__((ext_vector_type(8)))  short bfrag8;
typedef __attribute__((ext_vector_type(16))) float f32x16;

__device__ __forceinline__ float4 f4zero() { return make_float4(0.f, 0.f, 0.f, 0.f); }

__device__ __forceinline__ unsigned short f2bf(float f) {
    unsigned u = __float_as_uint(f);
    unsigned r = (u + 0x7fffu + ((u >> 16) & 1u)) >> 16;
    return (unsigned short)r;
}
__device__ __forceinline__ float bf2f(unsigned short b) {
    return __uint_as_float(((unsigned)b) << 16);
}
__device__ __forceinline__ void acc8(float* a, uint4 r) {
    a[0] += __uint_as_float(r.x << 16);
    a[1] += __uint_as_float(r.x & 0xffff0000u);
    a[2] += __uint_as_float(r.y << 16);
    a[3] += __uint_as_float(r.y & 0xffff0000u);
    a[4] += __uint_as_float(r.z << 16);
    a[5] += __uint_as_float(r.z & 0xffff0000u);
    a[6] += __uint_as_float(r.w << 16);
    a[7] += __uint_as_float(r.w & 0xffff0000u);
}

// ===========================================================================
// prep: W->Wt (bf16 T), x->bf16, zero deg, zero stats (3x8x256), zero out,
// zero dummy row.  grid = 512 + 6250 + 196 + 24 + 64 + 1 = 7047
// ===========================================================================
__global__ __launch_bounds__(256) void prep_kernel(
    const float* __restrict__ W1, const float* __restrict__ W2,
    const float* __restrict__ x, short* __restrict__ Wt,
    ushort4* __restrict__ Hb, int* __restrict__ deg, float* __restrict__ stats,
    float* __restrict__ outZero)
{
    int b = blockIdx.x, t = threadIdx.x;
    if (b < 512) {
        int idx = b * 256 + t;                 // 131072 = 8*128*128
        int m = idx >> 14, rem = idx & 16383;
        int k = rem >> 7, n = rem & 127;
        const float* W = (m < 4) ? (W1 + (size_t)m * 16384)
                                 : (W2 + (size_t)(m - 4) * 16384);
        Wt[(size_t)m * 16384 + n * 128 + k] = (short)f2bf(W[k * 128 + n]);
    } else if (b < 6762) {
        int i = (b - 512) * 256 + t;           // N*32 = 1,600,000 exactly
        float4 v = ((const float4*)x)[i];
        Hb[i] = make_ushort4(f2bf(v.x), f2bf(v.y), f2bf(v.z), f2bf(v.w));
    } else if (b < 6958) {
        int i = (b - 6762) * 256 + t;
        if (i < N_NODES) deg[i] = 0;
    } else if (b < 6982) {
        int i = (b - 6958) * 256 + t;          // 6144 floats: 3 x 8 x (sum||sq)
        stats[i] = 0.f;
    } else if (b < 7046) {
        int i = (b - 6982) * 256 + t;          // 16384 floats = out
        outZero[i] = 0.f;
    } else {
        // zero dummy row N_NODES (64 dwords = 256 B)
        if (t < 64) ((unsigned*)Hb)[(size_t)N_NODES * 64 + t] = 0u;
    }
}

// ===========================================================================
// CSR build (padded to multiple of 8 per row, ushort entries)
// ===========================================================================
__global__ __launch_bounds__(256) void hist_kernel(
    const int* __restrict__ dst, int* __restrict__ deg,
    unsigned short* __restrict__ edge_pos)
{
    int e = blockIdx.x * 256 + threadIdx.x;
    if (e < N_EDGES) edge_pos[e] = (unsigned short)atomicAdd(&deg[dst[e]], 1);
}

__global__ __launch_bounds__(256) void scan_block_kernel(
    const int* __restrict__ deg, int* __restrict__ row_ptr,
    int* __restrict__ blockSum)
{
    __shared__ int wsum[4];
    int t = threadIdx.x, b = blockIdx.x;
    int i = b * 256 + t;
    int v = (i < N_NODES) ? ((deg[i] + 7) & ~7) : 0;   // padded degree
    int lane = t & 63, wid = t >> 6;
    #pragma unroll
    for (int off = 1; off < 64; off <<= 1) {
        int u = __shfl_up(v, off, 64);
        if (lane >= off) v += u;
    }
    if (lane == 63) wsum[wid] = v;
    __syncthreads();
    int add = 0;
    for (int w = 0; w < wid; ++w) add += wsum[w];
    v += add;
    if (i < N_NODES) row_ptr[i + 1] = v;
    if (t == 255) blockSum[b] = v;
}

__global__ __launch_bounds__(256) void scan_fixup_kernel(
    const int* __restrict__ blockSum, int* __restrict__ row_ptr, int nb)
{
    __shared__ int wsum[4];
    __shared__ int sbuf[256];
    int t = threadIdx.x, b = blockIdx.x;
    int v = (t < nb) ? blockSum[t] : 0;
    int lane = t & 63, wid = t >> 6;
    #pragma unroll
    for (int off = 1; off < 64; off <<= 1) {
        int u = __shfl_up(v, off, 64);
        if (lane >= off) v += u;
    }
    if (lane == 63) wsum[wid] = v;
    __syncthreads();
    int add = 0;
    for (int w = 0; w < wid; ++w) add += wsum[w];
    sbuf[t] = v + add;
    __syncthreads();
    if (b == 0 && t == 0) row_ptr[0] = 0;
    if (b > 0) {
        int off = sbuf[b - 1];
        int i = b * 256 + t;
        if (i < N_NODES) row_ptr[i + 1] += off;
    }
}

// edge fill (blocks [0,3125)) + pad-slot fill with dummy node (blocks >= 3125)
__global__ __launch_bounds__(256) void fill_kernel(
    const int* __restrict__ src, const int* __restrict__ dst,
    const int* __restrict__ row_ptr, const unsigned short* __restrict__ edge_pos,
    const int* __restrict__ deg, unsigned short* __restrict__ csr_src)
{
    int b = blockIdx.x, t = threadIdx.x;
    if (b < 3125) {
        int e = b * 256 + t;
        if (e < N_EDGES)
            csr_src[row_ptr[dst[e]] + (int)edge_pos[e]] = (unsigned short)src[e];
    } else {
        int n = (b - 3125) * 256 + t;
        if (n < N_NODES) {
            int e0 = row_ptr[n] + deg[n];
            int e1 = row_ptr[n + 1];
            for (int j = e0; j < e1; ++j)
                csr_src[j] = (unsigned short)N_NODES;
        }
    }
}

// ===========================================================================
// bnapply: H <- relu(bn(H)) in-place.  stats = layer base [8][256] striped.
// ===========================================================================
__global__ __launch_bounds__(256) void bnapply_kernel(
    uint4* __restrict__ H, const float* __restrict__ stats,
    const float* __restrict__ gamma, const float* __restrict__ beta)
{
    __shared__ float sa[128], sb[128];
    int tid = threadIdx.x;
    if (tid < 128) {
        float s = 0.f, q = 0.f;
        #pragma unroll
        for (int k = 0; k < 8; ++k) {
            s += stats[k * 256 + tid];
            q += stats[k * 256 + 128 + tid];
        }
        const float invN = 1.0f / (float)N_NODES;
        float m = s * invN;
        float a = gamma[tid] * rsqrtf(q * invN - m * m + 1e-5f);
        sa[tid] = a;
        sb[tid] = beta[tid] - m * a;
    }
    __syncthreads();
    int id = blockIdx.x * 256 + tid;          // [0, 800000)
    int c0 = (id & 15) * 8;
    uint4 u = H[id];
    float lo, hi;
    lo = fmaxf(sa[c0 + 0] * __uint_as_float(u.x << 16)          + sb[c0 + 0], 0.f);
    hi = fmaxf(sa[c0 + 1] * __uint_as_float(u.x & 0xffff0000u) + sb[c0 + 1], 0.f);
    u.x = (unsigned)f2bf(lo) | ((unsigned)f2bf(hi) << 16);
    lo = fmaxf(sa[c0 + 2] * __uint_as_float(u.y << 16)          + sb[c0 + 2], 0.f);
    hi = fmaxf(sa[c0 + 3] * __uint_as_float(u.y & 0xffff0000u) + sb[c0 + 3], 0.f);
    u.y = (unsigned)f2bf(lo) | ((unsigned)f2bf(hi) << 16);
    lo = fmaxf(sa[c0 + 4] * __uint_as_float(u.z << 16)          + sb[c0 + 4], 0.f);
    hi = fmaxf(sa[c0 + 5] * __uint_as_float(u.z & 0xffff0000u) + sb[c0 + 5], 0.f);
    u.z = (unsigned)f2bf(lo) | ((unsigned)f2bf(hi) << 16);
    lo = fmaxf(sa[c0 + 6] * __uint_as_float(u.w << 16)          + sb[c0 + 6], 0.f);
    hi = fmaxf(sa[c0 + 7] * __uint_as_float(u.w & 0xffff0000u) + sb[c0 + 7], 0.f);
    u.w = (unsigned)f2bf(lo) | ((unsigned)f2bf(hi) << 16);
    H[id] = u;
}

// ===========================================================================
// Gather (padded CSR): A[n] = bf16((1+eps)*H[n] + sum H[j]).
// 16 lanes/node, uint4/lane, rows padded to x8 with dummy zero row.
// ===========================================================================
__global__ __launch_bounds__(256, 4) void gather_kernel(
    const uint4* __restrict__ H, const int* __restrict__ row_ptr,
    const unsigned short* __restrict__ csr, const float* __restrict__ epsp,
    uint4* __restrict__ A)
{
    int node = blockIdx.x * 16 + (threadIdx.x >> 4);
    int lane = threadIdx.x & 15;
    float eps1 = 1.0f + *epsp;
    int beg = row_ptr[node], end = row_ptr[node + 1];

    uint4 hv = H[(size_t)node * 16 + lane];
    float acc[8];
    acc[0] = eps1 * __uint_as_float(hv.x << 16);
    acc[1] = eps1 * __uint_as_float(hv.x & 0xffff0000u);
    acc[2] = eps1 * __uint_as_float(hv.y << 16);
    acc[3] = eps1 * __uint_as_float(hv.y & 0xffff0000u);
    acc[4] = eps1 * __uint_as_float(hv.z << 16);
    acc[5] = eps1 * __uint_as_float(hv.z & 0xffff0000u);
    acc[6] = eps1 * __uint_as_float(hv.w << 16);
    acc[7] = eps1 * __uint_as_float(hv.w & 0xffff0000u);

    int base = beg;
    int idx = (int)csr[base + lane];          // +16 slack allocated
    while (base < end) {
        int nb = base + 16;
        int nidx = 0;
        if (nb < end) nidx = (int)csr[nb + lane];
        int cnt = end - base;                 // multiple of 8
        int s0 = __shfl(idx, 0, 16), s1 = __shfl(idx, 1, 16);
        int s2 = __shfl(idx, 2, 16), s3 = __shfl(idx, 3, 16);
        int s4 = __shfl(idx, 4, 16), s5 = __shfl(idx, 5, 16);
        int s6 = __shfl(idx, 6, 16), s7 = __shfl(idx, 7, 16);
        uint4 u0 = H[(size_t)s0 * 16 + lane];
        uint4 u1 = H[(size_t)s1 * 16 + lane];
        uint4 u2 = H[(size_t)s2 * 16 + lane];
        uint4 u3 = H[(size_t)s3 * 16 + lane];
        uint4 u4 = H[(size_t)s4 * 16 + lane];
        uint4 u5 = H[(size_t)s5 * 16 + lane];
        uint4 u6 = H[(size_t)s6 * 16 + lane];
        uint4 u7 = H[(size_t)s7 * 16 + lane];
        if (cnt > 8) {
            int t0 = __shfl(idx,  8, 16), t1 = __shfl(idx,  9, 16);
            int t2 = __shfl(idx, 10, 16), t3 = __shfl(idx, 11, 16);
            int t4 = __shfl(idx, 12, 16), t5 = __shfl(idx, 13, 16);
            int t6 = __shfl(idx, 14, 16), t7 = __shfl(idx, 15, 16);
            uint4 w0 = H[(size_t)t0 * 16 + lane];
            uint4 w1 = H[(size_t)t1 * 16 + lane];
            uint4 w2 = H[(size_t)t2 * 16 + lane];
            uint4 w3 = H[(size_t)t3 * 16 + lane];
            uint4 w4 = H[(size_t)t4 * 16 + lane];
            uint4 w5 = H[(size_t)t5 * 16 + lane];
            uint4 w6 = H[(size_t)t6 * 16 + lane];
            uint4 w7 = H[(size_t)t7 * 16 + lane];
            acc8(acc, u0); acc8(acc, u1); acc8(acc, u2); acc8(acc, u3);
            acc8(acc, u4); acc8(acc, u5); acc8(acc, u6); acc8(acc, u7);
            acc8(acc, w0); acc8(acc, w1); acc8(acc, w2); acc8(acc, w3);
            acc8(acc, w4); acc8(acc, w5); acc8(acc, w6); acc8(acc, w7);
        } else {
            acc8(acc, u0); acc8(acc, u1); acc8(acc, u2); acc8(acc, u3);
            acc8(acc, u4); acc8(acc, u5); acc8(acc, u6); acc8(acc, u7);
        }
        idx = nidx; base = nb;
    }
    uint4 o;
    o.x = (unsigned)f2bf(acc[0]) | ((unsigned)f2bf(acc[1]) << 16);
    o.y = (unsigned)f2bf(acc[2]) | ((unsigned)f2bf(acc[3]) << 16);
    o.z = (unsigned)f2bf(acc[4]) | ((unsigned)f2bf(acc[5]) << 16);
    o.w = (unsigned)f2bf(acc[6]) | ((unsigned)f2bf(acc[7]) << 16);
    A[(size_t)node * 16 + lane] = o;
}

// ===========================================================================
// Fused MLP:  z2 = (relu(A @ W1 + b1)) @ W2 + b2, bf16 MFMA 32x32x16.
// Stats striped 8x by blockIdx to kill same-line atomic serialization.
// Last layer: global_add_pool fused into epilogue (poolOut != null).
// ===========================================================================
__global__ __launch_bounds__(256, 3) void mlp_fused_kernel(
    const ushort* __restrict__ A,
    const short* __restrict__ Wt1,
    const short* __restrict__ Wt2,
    const float* __restrict__ bias1,
    const float* __restrict__ bias2,
    ushort* __restrict__ Hout,
    float* __restrict__ statsBase,     // [8][256] striped, or null
    const int* __restrict__ batch,
    float* __restrict__ poolOut,
    int M)
{
    __shared__ __align__(16) short Wlds[128 * 128];   // 32 KB
    __shared__ __align__(16) short zlds[2][32 * 128]; // 16 KB
    __shared__ float ssum[128];
    __shared__ float ssq[128];

    const int tid  = threadIdx.x;
    const int wv   = tid >> 6;
    const int lane = tid & 63;
    const int half = lane >> 5;
    const int ln   = lane & 31;
    const int rg   = wv & 1;
    const int ch   = wv >> 1;
    const int row0 = blockIdx.x * 64 + rg * 32;
    const bool doStats = (statsBase != nullptr);
    if (doStats && tid < 128) { ssum[tid] = 0.f; ssq[tid] = 0.f; }

    short* zw = &zlds[rg][0];

    // ---- stage W1 -> Wlds (chunk c of row n at c^(n&15)) ----
    {
        const int4* Wg = (const int4*)Wt1;
        int4* Wl = (int4*)Wlds;
        #pragma unroll
        for (int i = 0; i < 8; ++i) {
            int id = i * 256 + tid;            // 2048 int4
            int n = id >> 4, c = id & 15;
            Wl[n * 16 + (c ^ (n & 15))] = Wg[id];
        }
    }
    __syncthreads();   // S0: W1 staged, ssum init

    // ---- GEMM1: z1 = relu(A@W1 + b1) -> zlds[rg] ----
    {
        f32x16 acc[2];
        #pragma unroll
        for (int ci = 0; ci < 2; ++ci)
            #pragma unroll
            for (int r = 0; r < 16; ++r) acc[ci][r] = 0.f;

        bfrag8 af[8];
        int rowc = min(row0 + ln, M - 1);
        const ushort* ap = A + (size_t)rowc * 128 + half * 8;
        #pragma unroll
        for (int kk = 0; kk < 8; ++kk)
            af[kk] = *(const bfrag8*)(ap + kk * 16);

        #pragma unroll
        for (int kk = 0; kk < 8; ++kk) {
            #pragma unroll
            for (int ci = 0; ci < 2; ++ci) {
                int n = (ch * 2 + ci) * 32 + ln;
                int c = kk * 2 + half;
                bfrag8 bf = *(const bfrag8*)(Wlds + n * 128 + ((c ^ (n & 15)) << 3));
                acc[ci] = __builtin_amdgcn_mfma_f32_32x32x16_bf16(
                    af[kk], bf, acc[ci], 0, 0, 0);
            }
        }
        #pragma unroll
        for (int ci = 0; ci < 2; ++ci) {
            int col = (ch * 2 + ci) * 32 + ln;
            int cc = col >> 3, co = col & 7;
            float bv = bias1[col];
            #pragma unroll
            for (int r = 0; r < 16; ++r) {
                int rloc = (r & 3) + 8 * (r >> 2) + 4 * half;
                float v = fmaxf(acc[ci][r] + bv, 0.f);
                zw[rloc * 128 + ((cc ^ (rloc & 15)) << 3) + co] = (short)f2bf(v);
            }
        }
    }
    __syncthreads();   // S1: z1 complete, G1 Wlds reads done

    // ---- stage W2 -> Wlds; preload af2 from zlds[rg] ----
    bfrag8 af2[8];
    #pragma unroll
    for (int kk = 0; kk < 8; ++kk) {
        int c = kk * 2 + half;
        af2[kk] = *(const bfrag8*)(zw + ln * 128 + ((c ^ (ln & 15)) << 3));
    }
    {
        const int4* Wg = (const int4*)Wt2;
        int4* Wl = (int4*)Wlds;
        #pragma unroll
        for (int i = 0; i < 8; ++i) {
            int id = i * 256 + tid;
            int n = id >> 4, c = id & 15;
            Wl[n * 16 + (c ^ (n & 15))] = Wg[id];
        }
    }
    __syncthreads();   // S2: W2 staged, all af2 preloads done

    // ---- GEMM2: z2 = z1 @ W2 + b2 -> zlds[rg]; stats on fp32 values ----
    {
        f32x16 acc[2];
        #pragma unroll
        for (int ci = 0; ci < 2; ++ci)
            #pragma unroll
            for (int r = 0; r < 16; ++r) acc[ci][r] = 0.f;

        #pragma unroll
        for (int kk = 0; kk < 8; ++kk) {
            #pragma unroll
            for (int ci = 0; ci < 2; ++ci) {
                int n = (ch * 2 + ci) * 32 + ln;
                int c = kk * 2 + half;
                bfrag8 bf = *(const bfrag8*)(Wlds + n * 128 + ((c ^ (n & 15)) << 3));
                acc[ci] = __builtin_amdgcn_mfma_f32_32x32x16_bf16(
                    af2[kk], bf, acc[ci], 0, 0, 0);
            }
        }
        #pragma unroll
        for (int ci = 0; ci < 2; ++ci) {
            int col = (ch * 2 + ci) * 32 + ln;
            int cc = col >> 3, co = col & 7;
            float bv = bias2[col];
            float s = 0.f, sq = 0.f;
            #pragma unroll
            for (int r = 0; r < 16; ++r) {
                int rloc = (r & 3) + 8 * (r >> 2) + 4 * half;
                float v = acc[ci][r] + bv;
                zw[rloc * 128 + ((cc ^ (rloc & 15)) << 3) + co] = (short)f2bf(v);
                if (row0 + rloc < M) { s += v; sq += v * v; }
            }
            if (doStats) {
                s  += __shfl_xor(s, 32);
                sq += __shfl_xor(sq, 32);
                if (half == 0) {
                    atomicAdd(&ssum[col], s);
                    atomicAdd(&ssq[col], sq);
                }
            }
        }
    }
    __syncthreads();   // S3: z2 complete, ssum atomics done

    if (poolOut == nullptr) {
        // ---- coalesced store: zlds -> Hout (64 rows x 16 int4) ----
        int4* Ho = (int4*)Hout;
        #pragma unroll
        for (int i = 0; i < 4; ++i) {
            int id = i * 256 + tid;            // 1024 int4
            int r = id >> 4, c = id & 15;
            int rl = r & 31;
            int grow = blockIdx.x * 64 + r;
            if (grow < M)
                Ho[(size_t)grow * 16 + c] =
                    ((const int4*)&zlds[r >> 5][0])[rl * 16 + (c ^ (rl & 15))];
        }
    } else {
        // ---- fused global_add_pool: sum rows by (sorted) batch id ----
        int c4 = tid & 31;                     // column quad c4*4..+3
        int rl8 = tid >> 5;                    // 8 row-lanes
        int cc = c4 >> 1, co = (c4 & 1) * 4;
        float4 ap = f4zero();
        int gcur = -1;
        for (int i = rl8; i < 64; i += 8) {
            int grow = blockIdx.x * 64 + i;
            if (grow >= M) break;
            int g = batch[grow];
            if (g != gcur) {
                if (gcur >= 0) {
                    float* o = poolOut + gcur * D + c4 * 4;
                    atomicAdd(o + 0, ap.x); atomicAdd(o + 1, ap.y);
                    atomicAdd(o + 2, ap.z); atomicAdd(o + 3, ap.w);
                }
                gcur = g; ap = f4zero();
            }
            const short* zr = &zlds[i >> 5][0];
            int rl = i & 31;
            const ushort4 u = *(const ushort4*)
                ((const ushort*)(zr + rl * 128 + ((cc ^ (rl & 15)) << 3) + co));
            ap.x += bf2f(u.x); ap.y += bf2f(u.y);
            ap.z += bf2f(u.z); ap.w += bf2f(u.w);
        }
        if (gcur >= 0) {
            float* o = poolOut + gcur * D + c4 * 4;
            atomicAdd(o + 0, ap.x); atomicAdd(o + 1, ap.y);
            atomicAdd(o + 2, ap.z); atomicAdd(o + 3, ap.w);
        }
    }
    if (doStats && tid < 128) {
        float* slot = statsBase + (size_t)(blockIdx.x & 7) * 256;
        atomicAdd(&slot[tid],       ssum[tid]);
        atomicAdd(&slot[128 + tid], ssq[tid]);
    }
}

extern "C" void kernel_launch(void* const* d_in, const int* in_sizes, int n_in,
                              void* d_out, int out_size, void* d_ws, size_t ws_size,
                              hipStream_t stream)
{
    const float* x     = (const float*)d_in[0];
    const int*   ei    = (const int*)d_in[1];
    const int*   batch = (const int*)d_in[2];
    const float* W1    = (const float*)d_in[3];
    const float* b1    = (const float*)d_in[4];
    const float* W2    = (const float*)d_in[5];
    const float* b2    = (const float*)d_in[6];
    const float* eps   = (const float*)d_in[7];
    const float* gamma = (const float*)d_in[8];
    const float* beta  = (const float*)d_in[9];
    float* out = (float*)d_out;

    // ---- workspace layout ----
    // Hb has N+1 rows (row N = dummy zero row for CSR padding)
    unsigned short* Hb  = (unsigned short*)d_ws;              // [N+1,128] bf16
    unsigned short* Abf = Hb + (size_t)(N_NODES + 1) * D;     // [N,128] bf16
    float* stats    = (float*)(Abf + (size_t)N_NODES * D);    // [3][8][256]
    int*   deg      = (int*)(stats + 3 * 2048);               // [N]
    int*   row_ptr  = deg + N_NODES;                          // [N+1]
    int*   blockSum = row_ptr + N_NODES + 1;                  // [256]
    unsigned short* edge_pos = (unsigned short*)(blockSum + 256);  // [E]
    unsigned short* csr_src  = edge_pos + N_EDGES;            // [E + 7N + 16]
    short* Wt       = (short*)(csr_src + N_EDGES + 7 * N_NODES + 16); // [8][128][128]

    const int* src = ei;
    const int* dst = ei + N_EDGES;

    const int edgeBlocks   = (N_EDGES + 255) / 256;      // 3125
    const int scanBlocks   = (N_NODES + 255) / 256;      // 196
    const int gatherBlocks = (N_NODES + 15) / 16;        // 3125
    const int bnBlocks     = (N_NODES * 16) / 256;       // 3125 exact
    const int gemmBlocks   = (N_NODES + 63) / 64;        // 782

    prep_kernel<<<7047, 256, 0, stream>>>(W1, W2, x, Wt, (ushort4*)Hb,
                                          deg, stats, out);
    hist_kernel<<<edgeBlocks, 256, 0, stream>>>(dst, deg, edge_pos);
    scan_block_kernel<<<scanBlocks, 256, 0, stream>>>(deg, row_ptr, blockSum);
    scan_fixup_kernel<<<scanBlocks, 256, 0, stream>>>(blockSum, row_ptr, scanBlocks);
    fill_kernel<<<edgeBlocks + scanBlocks, 256, 0, stream>>>(
        src, dst, row_ptr, edge_pos, deg, csr_src);

    for (int layer = 0; layer < 4; ++layer) {
        const bool bn = (layer < 3);
        if (layer > 0) {
            bnapply_kernel<<<bnBlocks, 256, 0, stream>>>(
                (uint4*)Hb, stats + (size_t)(layer - 1) * 2048,
                gamma + (size_t)(layer - 1) * D, beta + (size_t)(layer - 1) * D);
        }
        gather_kernel<<<gatherBlocks, 256, 0, stream>>>(
            (const uint4*)Hb, row_ptr, csr_src, eps + layer, (uint4*)Abf);
        mlp_fused_kernel<<<gemmBlocks, 256, 0, stream>>>(
            Abf, Wt + (size_t)layer * 16384, Wt + (size_t)(4 + layer) * 16384,
            b1 + (size_t)layer * D, b2 + (size_t)layer * D, Hb,
            bn ? stats + (size_t)layer * 2048 : nullptr,
            bn ? nullptr : batch,
            bn ? nullptr : out, N_NODES);
    }
}

// Round 4
// 342.712 us; speedup vs baseline: 1.2301x; 1.0532x over previous
//
#include <hip/hip_runtime.h>

#define N_NODES 50000
#define N_EDGES 800000
#define D 128
#define NUM_GRAPHS 128

typedef __attribute__((ext_vector_type(8)))  short bfrag8;
typedef __attribute__((ext_vector_type(16))) float f32x16;

__device__ __forceinline__ float4 f4zero() { return make_float4(0.f, 0.f, 0.f, 0.f); }

__device__ __forceinline__ unsigned short f2bf(float f) {
    unsigned u = __float_as_uint(f);
    unsigned r = (u + 0x7fffu + ((u >> 16) & 1u)) >> 16;
    return (unsigned short)r;
}
__device__ __forceinline__ float bf2f(unsigned short b) {
    return __uint_as_float(((unsigned)b) << 16);
}
__device__ __forceinline__ void acc8(float* a, uint4 r) {
    a[0] += __uint_as_float(r.x << 16);
    a[1] += __uint_as_float(r.x & 0xffff0000u);
    a[2] += __uint_as_float(r.y << 16);
    a[3] += __uint_as_float(r.y & 0xffff0000u);
    a[4] += __uint_as_float(r.z << 16);
    a[5] += __uint_as_float(r.z & 0xffff0000u);
    a[6] += __uint_as_float(r.w << 16);
    a[7] += __uint_as_float(r.w & 0xffff0000u);
}

// ===========================================================================
// prep: W->Wt (bf16 T), x->bf16, zero deg, zero stats (3x8x256), zero out,
// zero dummy rows of BOTH H buffers.  grid = 512+6250+196+24+64+1 = 7047
// ===========================================================================
__global__ __launch_bounds__(256) void prep_kernel(
    const float* __restrict__ W1, const float* __restrict__ W2,
    const float* __restrict__ x, short* __restrict__ Wt,
    ushort4* __restrict__ Hb, unsigned* __restrict__ HcDummy,
    int* __restrict__ deg, float* __restrict__ stats,
    float* __restrict__ outZero)
{
    int b = blockIdx.x, t = threadIdx.x;
    if (b < 512) {
        int idx = b * 256 + t;                 // 131072 = 8*128*128
        int m = idx >> 14, rem = idx & 16383;
        int k = rem >> 7, n = rem & 127;
        const float* W = (m < 4) ? (W1 + (size_t)m * 16384)
                                 : (W2 + (size_t)(m - 4) * 16384);
        Wt[(size_t)m * 16384 + n * 128 + k] = (short)f2bf(W[k * 128 + n]);
    } else if (b < 6762) {
        int i = (b - 512) * 256 + t;           // N*32 = 1,600,000 exactly
        float4 v = ((const float4*)x)[i];
        Hb[i] = make_ushort4(f2bf(v.x), f2bf(v.y), f2bf(v.z), f2bf(v.w));
    } else if (b < 6958) {
        int i = (b - 6762) * 256 + t;
        if (i < N_NODES) deg[i] = 0;
    } else if (b < 6982) {
        int i = (b - 6958) * 256 + t;          // 6144 floats: 3 x 8 x (sum||sq)
        stats[i] = 0.f;
    } else if (b < 7046) {
        int i = (b - 6982) * 256 + t;          // 16384 floats = out
        outZero[i] = 0.f;
    } else {
        // zero dummy row N_NODES of both H buffers (64 dwords each)
        if (t < 64)       ((unsigned*)Hb)[(size_t)N_NODES * 64 + t] = 0u;
        else if (t < 128) HcDummy[t - 64] = 0u;
    }
}

// ===========================================================================
// CSR build (padded to multiple of 8 per row, ushort entries)
// ===========================================================================
__global__ __launch_bounds__(256) void hist_kernel(
    const int* __restrict__ dst, int* __restrict__ deg,
    unsigned short* __restrict__ edge_pos)
{
    int e = blockIdx.x * 256 + threadIdx.x;
    if (e < N_EDGES) edge_pos[e] = (unsigned short)atomicAdd(&deg[dst[e]], 1);
}

__global__ __launch_bounds__(256) void scan_block_kernel(
    const int* __restrict__ deg, int* __restrict__ row_ptr,
    int* __restrict__ blockSum)
{
    __shared__ int wsum[4];
    int t = threadIdx.x, b = blockIdx.x;
    int i = b * 256 + t;
    int v = (i < N_NODES) ? ((deg[i] + 7) & ~7) : 0;   // padded degree
    int lane = t & 63, wid = t >> 6;
    #pragma unroll
    for (int off = 1; off < 64; off <<= 1) {
        int u = __shfl_up(v, off, 64);
        if (lane >= off) v += u;
    }
    if (lane == 63) wsum[wid] = v;
    __syncthreads();
    int add = 0;
    for (int w = 0; w < wid; ++w) add += wsum[w];
    v += add;
    if (i < N_NODES) row_ptr[i + 1] = v;
    if (t == 255) blockSum[b] = v;
}

__global__ __launch_bounds__(256) void scan_fixup_kernel(
    const int* __restrict__ blockSum, int* __restrict__ row_ptr, int nb)
{
    __shared__ int wsum[4];
    __shared__ int sbuf[256];
    int t = threadIdx.x, b = blockIdx.x;
    int v = (t < nb) ? blockSum[t] : 0;
    int lane = t & 63, wid = t >> 6;
    #pragma unroll
    for (int off = 1; off < 64; off <<= 1) {
        int u = __shfl_up(v, off, 64);
        if (lane >= off) v += u;
    }
    if (lane == 63) wsum[wid] = v;
    __syncthreads();
    int add = 0;
    for (int w = 0; w < wid; ++w) add += wsum[w];
    sbuf[t] = v + add;
    __syncthreads();
    if (b == 0 && t == 0) row_ptr[0] = 0;
    if (b > 0) {
        int off = sbuf[b - 1];
        int i = b * 256 + t;
        if (i < N_NODES) row_ptr[i + 1] += off;
    }
}

// edge fill (blocks [0,3125)) + pad-slot fill with dummy node (blocks >= 3125)
__global__ __launch_bounds__(256) void fill_kernel(
    const int* __restrict__ src, const int* __restrict__ dst,
    const int* __restrict__ row_ptr, const unsigned short* __restrict__ edge_pos,
    const int* __restrict__ deg, unsigned short* __restrict__ csr_src)
{
    int b = blockIdx.x, t = threadIdx.x;
    if (b < 3125) {
        int e = b * 256 + t;
        if (e < N_EDGES)
            csr_src[row_ptr[dst[e]] + (int)edge_pos[e]] = (unsigned short)src[e];
    } else {
        int n = (b - 3125) * 256 + t;
        if (n < N_NODES) {
            int e0 = row_ptr[n] + deg[n];
            int e1 = row_ptr[n + 1];
            for (int j = e0; j < e1; ++j)
                csr_src[j] = (unsigned short)N_NODES;
        }
    }
}

// ===========================================================================
// bnapply: H <- relu(bn(H)) in-place.  stats = layer base [8][256] striped.
// ===========================================================================
__global__ __launch_bounds__(256) void bnapply_kernel(
    uint4* __restrict__ H, const float* __restrict__ stats,
    const float* __restrict__ gamma, const float* __restrict__ beta)
{
    __shared__ float sa[128], sb[128];
    int tid = threadIdx.x;
    if (tid < 128) {
        float s = 0.f, q = 0.f;
        #pragma unroll
        for (int k = 0; k < 8; ++k) {
            s += stats[k * 256 + tid];
            q += stats[k * 256 + 128 + tid];
        }
        const float invN = 1.0f / (float)N_NODES;
        float m = s * invN;
        float a = gamma[tid] * rsqrtf(q * invN - m * m + 1e-5f);
        sa[tid] = a;
        sb[tid] = beta[tid] - m * a;
    }
    __syncthreads();
    int id = blockIdx.x * 256 + tid;          // [0, 800000)
    int c0 = (id & 15) * 8;
    uint4 u = H[id];
    float lo, hi;
    lo = fmaxf(sa[c0 + 0] * __uint_as_float(u.x << 16)          + sb[c0 + 0], 0.f);
    hi = fmaxf(sa[c0 + 1] * __uint_as_float(u.x & 0xffff0000u) + sb[c0 + 1], 0.f);
    u.x = (unsigned)f2bf(lo) | ((unsigned)f2bf(hi) << 16);
    lo = fmaxf(sa[c0 + 2] * __uint_as_float(u.y << 16)          + sb[c0 + 2], 0.f);
    hi = fmaxf(sa[c0 + 3] * __uint_as_float(u.y & 0xffff0000u) + sb[c0 + 3], 0.f);
    u.y = (unsigned)f2bf(lo) | ((unsigned)f2bf(hi) << 16);
    lo = fmaxf(sa[c0 + 4] * __uint_as_float(u.z << 16)          + sb[c0 + 4], 0.f);
    hi = fmaxf(sa[c0 + 5] * __uint_as_float(u.z & 0xffff0000u) + sb[c0 + 5], 0.f);
    u.z = (unsigned)f2bf(lo) | ((unsigned)f2bf(hi) << 16);
    lo = fmaxf(sa[c0 + 6] * __uint_as_float(u.w << 16)          + sb[c0 + 6], 0.f);
    hi = fmaxf(sa[c0 + 7] * __uint_as_float(u.w & 0xffff0000u) + sb[c0 + 7], 0.f);
    u.w = (unsigned)f2bf(lo) | ((unsigned)f2bf(hi) << 16);
    H[id] = u;
}

// ===========================================================================
// FUSED LAYER: gather 64 rows -> zlds (A layout), then
// z2 = (relu(A @ W1 + b1)) @ W2 + b2 via bf16 MFMA 32x32x16.
// Hin != Hout (ping-pong; fused kernel reads random rows of Hin while
// writing Hout). A never touches global memory.
// Stats striped 8x by blockIdx. Last layer: pool fused, no Hout store.
// ===========================================================================
__global__ __launch_bounds__(256, 3) void layer_kernel(
    const ushort* __restrict__ Hin,
    const int* __restrict__ row_ptr,
    const unsigned short* __restrict__ csr,
    const float* __restrict__ epsp,
    const short* __restrict__ Wt1,
    const short* __restrict__ Wt2,
    const float* __restrict__ bias1,
    const float* __restrict__ bias2,
    ushort* __restrict__ Hout,
    float* __restrict__ statsBase,     // [8][256] striped, or null
    const int* __restrict__ batch,
    float* __restrict__ poolOut,
    int M)
{
    __shared__ __align__(16) short Wlds[128 * 128];   // 32 KB
    __shared__ __align__(16) short zlds[2][32 * 128]; // 16 KB (A / z1 / z2)
    __shared__ float ssum[128];
    __shared__ float ssq[128];

    const int tid  = threadIdx.x;
    const int wv   = tid >> 6;
    const int lane = tid & 63;
    const int half = lane >> 5;
    const int ln   = lane & 31;
    const int rg   = wv & 1;
    const int ch   = wv >> 1;
    const int row0 = blockIdx.x * 64 + rg * 32;
    const bool doStats = (statsBase != nullptr);
    if (doStats && tid < 128) { ssum[tid] = 0.f; ssq[tid] = 0.f; }

    short* zw = &zlds[rg][0];

    // ---- Phase G: gather 64 rows into zlds in A-fragment layout ----
    {
        const uint4* H4 = (const uint4*)Hin;
        const float eps1 = 1.0f + *epsp;
        const int gl = tid & 15;              // chunk lane
        #pragma unroll
        for (int it = 0; it < 4; ++it) {
            int r = it * 16 + (tid >> 4);     // local row 0..63
            int node = blockIdx.x * 64 + r;
            float acc[8] = {0.f, 0.f, 0.f, 0.f, 0.f, 0.f, 0.f, 0.f};
            if (node < M) {
                uint4 hv = H4[(size_t)node * 16 + gl];
                acc[0] = eps1 * __uint_as_float(hv.x << 16);
                acc[1] = eps1 * __uint_as_float(hv.x & 0xffff0000u);
                acc[2] = eps1 * __uint_as_float(hv.y << 16);
                acc[3] = eps1 * __uint_as_float(hv.y & 0xffff0000u);
                acc[4] = eps1 * __uint_as_float(hv.z << 16);
                acc[5] = eps1 * __uint_as_float(hv.z & 0xffff0000u);
                acc[6] = eps1 * __uint_as_float(hv.w << 16);
                acc[7] = eps1 * __uint_as_float(hv.w & 0xffff0000u);
                int beg = row_ptr[node], end = row_ptr[node + 1];
                int base = beg;
                int idx = (int)csr[base + gl];     // +16 slack allocated
                while (base < end) {
                    int nb = base + 16;
                    int nidx = 0;
                    if (nb < end) nidx = (int)csr[nb + gl];
                    int cnt = end - base;          // multiple of 8
                    int s0 = __shfl(idx, 0, 16), s1 = __shfl(idx, 1, 16);
                    int s2 = __shfl(idx, 2, 16), s3 = __shfl(idx, 3, 16);
                    int s4 = __shfl(idx, 4, 16), s5 = __shfl(idx, 5, 16);
                    int s6 = __shfl(idx, 6, 16), s7 = __shfl(idx, 7, 16);
                    uint4 u0 = H4[(size_t)s0 * 16 + gl];
                    uint4 u1 = H4[(size_t)s1 * 16 + gl];
                    uint4 u2 = H4[(size_t)s2 * 16 + gl];
                    uint4 u3 = H4[(size_t)s3 * 16 + gl];
                    uint4 u4 = H4[(size_t)s4 * 16 + gl];
                    uint4 u5 = H4[(size_t)s5 * 16 + gl];
                    uint4 u6 = H4[(size_t)s6 * 16 + gl];
                    uint4 u7 = H4[(size_t)s7 * 16 + gl];
                    if (cnt > 8) {
                        int t0 = __shfl(idx,  8, 16), t1 = __shfl(idx,  9, 16);
                        int t2 = __shfl(idx, 10, 16), t3 = __shfl(idx, 11, 16);
                        int t4 = __shfl(idx, 12, 16), t5 = __shfl(idx, 13, 16);
                        int t6 = __shfl(idx, 14, 16), t7 = __shfl(idx, 15, 16);
                        uint4 w0 = H4[(size_t)t0 * 16 + gl];
                        uint4 w1 = H4[(size_t)t1 * 16 + gl];
                        uint4 w2 = H4[(size_t)t2 * 16 + gl];
                        uint4 w3 = H4[(size_t)t3 * 16 + gl];
                        uint4 w4 = H4[(size_t)t4 * 16 + gl];
                        uint4 w5 = H4[(size_t)t5 * 16 + gl];
                        uint4 w6 = H4[(size_t)t6 * 16 + gl];
                        uint4 w7 = H4[(size_t)t7 * 16 + gl];
                        acc8(acc, u0); acc8(acc, u1); acc8(acc, u2); acc8(acc, u3);
                        acc8(acc, u4); acc8(acc, u5); acc8(acc, u6); acc8(acc, u7);
                        acc8(acc, w0); acc8(acc, w1); acc8(acc, w2); acc8(acc, w3);
                        acc8(acc, w4); acc8(acc, w5); acc8(acc, w6); acc8(acc, w7);
                    } else {
                        acc8(acc, u0); acc8(acc, u1); acc8(acc, u2); acc8(acc, u3);
                        acc8(acc, u4); acc8(acc, u5); acc8(acc, u6); acc8(acc, u7);
                    }
                    idx = nidx; base = nb;
                }
            }
            uint4 o;
            o.x = (unsigned)f2bf(acc[0]) | ((unsigned)f2bf(acc[1]) << 16);
            o.y = (unsigned)f2bf(acc[2]) | ((unsigned)f2bf(acc[3]) << 16);
            o.z = (unsigned)f2bf(acc[4]) | ((unsigned)f2bf(acc[5]) << 16);
            o.w = (unsigned)f2bf(acc[6]) | ((unsigned)f2bf(acc[7]) << 16);
            int rl = r & 31;
            ((uint4*)&zlds[r >> 5][0])[rl * 16 + (gl ^ (rl & 15))] = o;
        }
    }
    __syncthreads();   // S0: A in zlds, ssum init

    // ---- preload af (A frags) from zlds; stage W1 -> Wlds ----
    bfrag8 af[8];
    #pragma unroll
    for (int kk = 0; kk < 8; ++kk) {
        int c = kk * 2 + half;
        af[kk] = *(const bfrag8*)(zw + ln * 128 + ((c ^ (ln & 15)) << 3));
    }
    {
        const int4* Wg = (const int4*)Wt1;
        int4* Wl = (int4*)Wlds;
        #pragma unroll
        for (int i = 0; i < 8; ++i) {
            int id = i * 256 + tid;            // 2048 int4
            int n = id >> 4, c = id & 15;
            Wl[n * 16 + (c ^ (n & 15))] = Wg[id];
        }
    }
    __syncthreads();   // S1: W1 staged, af preloads done

    // ---- GEMM1: z1 = relu(A@W1 + b1) -> zlds ----
    {
        f32x16 acc[2];
        #pragma unroll
        for (int ci = 0; ci < 2; ++ci)
            #pragma unroll
            for (int r = 0; r < 16; ++r) acc[ci][r] = 0.f;

        #pragma unroll
        for (int kk = 0; kk < 8; ++kk) {
            #pragma unroll
            for (int ci = 0; ci < 2; ++ci) {
                int n = (ch * 2 + ci) * 32 + ln;
                int c = kk * 2 + half;
                bfrag8 bf = *(const bfrag8*)(Wlds + n * 128 + ((c ^ (n & 15)) << 3));
                acc[ci] = __builtin_amdgcn_mfma_f32_32x32x16_bf16(
                    af[kk], bf, acc[ci], 0, 0, 0);
            }
        }
        #pragma unroll
        for (int ci = 0; ci < 2; ++ci) {
            int col = (ch * 2 + ci) * 32 + ln;
            int cc = col >> 3, co = col & 7;
            float bv = bias1[col];
            #pragma unroll
            for (int r = 0; r < 16; ++r) {
                int rloc = (r & 3) + 8 * (r >> 2) + 4 * half;
                float v = fmaxf(acc[ci][r] + bv, 0.f);
                zw[rloc * 128 + ((cc ^ (rloc & 15)) << 3) + co] = (short)f2bf(v);
            }
        }
    }
    __syncthreads();   // S2: z1 complete, G1 Wlds/zlds reads done

    // ---- stage W2 -> Wlds; preload af2 from zlds ----
    bfrag8 af2[8];
    #pragma unroll
    for (int kk = 0; kk < 8; ++kk) {
        int c = kk * 2 + half;
        af2[kk] = *(const bfrag8*)(zw + ln * 128 + ((c ^ (ln & 15)) << 3));
    }
    {
        const int4* Wg = (const int4*)Wt2;
        int4* Wl = (int4*)Wlds;
        #pragma unroll
        for (int i = 0; i < 8; ++i) {
            int id = i * 256 + tid;
            int n = id >> 4, c = id & 15;
            Wl[n * 16 + (c ^ (n & 15))] = Wg[id];
        }
    }
    __syncthreads();   // S3: W2 staged, all af2 preloads done

    // ---- GEMM2: z2 = z1 @ W2 + b2 -> zlds; stats on fp32 values ----
    {
        f32x16 acc[2];
        #pragma unroll
        for (int ci = 0; ci < 2; ++ci)
            #pragma unroll
            for (int r = 0; r < 16; ++r) acc[ci][r] = 0.f;

        #pragma unroll
        for (int kk = 0; kk < 8; ++kk) {
            #pragma unroll
            for (int ci = 0; ci < 2; ++ci) {
                int n = (ch * 2 + ci) * 32 + ln;
                int c = kk * 2 + half;
                bfrag8 bf = *(const bfrag8*)(Wlds + n * 128 + ((c ^ (n & 15)) << 3));
                acc[ci] = __builtin_amdgcn_mfma_f32_32x32x16_bf16(
                    af2[kk], bf, acc[ci], 0, 0, 0);
            }
        }
        #pragma unroll
        for (int ci = 0; ci < 2; ++ci) {
            int col = (ch * 2 + ci) * 32 + ln;
            int cc = col >> 3, co = col & 7;
            float bv = bias2[col];
            float s = 0.f, sq = 0.f;
            #pragma unroll
            for (int r = 0; r < 16; ++r) {
                int rloc = (r & 3) + 8 * (r >> 2) + 4 * half;
                float v = acc[ci][r] + bv;
                zw[rloc * 128 + ((cc ^ (rloc & 15)) << 3) + co] = (short)f2bf(v);
                if (row0 + rloc < M) { s += v; sq += v * v; }
            }
            if (doStats) {
                s  += __shfl_xor(s, 32);
                sq += __shfl_xor(sq, 32);
                if (half == 0) {
                    atomicAdd(&ssum[col], s);
                    atomicAdd(&ssq[col], sq);
                }
            }
        }
    }
    __syncthreads();   // S4: z2 complete, ssum atomics done

    if (poolOut == nullptr) {
        // ---- coalesced store: zlds -> Hout (64 rows x 16 int4) ----
        int4* Ho = (int4*)Hout;
        #pragma unroll
        for (int i = 0; i < 4; ++i) {
            int id = i * 256 + tid;            // 1024 int4
            int r = id >> 4, c = id & 15;
            int rl = r & 31;
            int grow = blockIdx.x * 64 + r;
            if (grow < M)
                Ho[(size_t)grow * 16 + c] =
                    ((const int4*)&zlds[r >> 5][0])[rl * 16 + (c ^ (rl & 15))];
        }
    } else {
        // ---- fused global_add_pool: sum rows by (sorted) batch id ----
        int c4 = tid & 31;                     // column quad c4*4..+3
        int rl8 = tid >> 5;                    // 8 row-lanes
        int cc = c4 >> 1, co = (c4 & 1) * 4;
        float4 ap = f4zero();
        int gcur = -1;
        for (int i = rl8; i < 64; i += 8) {
            int grow = blockIdx.x * 64 + i;
            if (grow >= M) break;
            int g = batch[grow];
            if (g != gcur) {
                if (gcur >= 0) {
                    float* o = poolOut + gcur * D + c4 * 4;
                    atomicAdd(o + 0, ap.x); atomicAdd(o + 1, ap.y);
                    atomicAdd(o + 2, ap.z); atomicAdd(o + 3, ap.w);
                }
                gcur = g; ap = f4zero();
            }
            const short* zr = &zlds[i >> 5][0];
            int rl = i & 31;
            const ushort4 u = *(const ushort4*)
                ((const ushort*)(zr + rl * 128 + ((cc ^ (rl & 15)) << 3) + co));
            ap.x += bf2f(u.x); ap.y += bf2f(u.y);
            ap.z += bf2f(u.z); ap.w += bf2f(u.w);
        }
        if (gcur >= 0) {
            float* o = poolOut + gcur * D + c4 * 4;
            atomicAdd(o + 0, ap.x); atomicAdd(o + 1, ap.y);
            atomicAdd(o + 2, ap.z); atomicAdd(o + 3, ap.w);
        }
    }
    if (doStats && tid < 128) {
        float* slot = statsBase + (size_t)(blockIdx.x & 7) * 256;
        atomicAdd(&slot[tid],       ssum[tid]);
        atomicAdd(&slot[128 + tid], ssq[tid]);
    }
}

extern "C" void kernel_launch(void* const* d_in, const int* in_sizes, int n_in,
                              void* d_out, int out_size, void* d_ws, size_t ws_size,
                              hipStream_t stream)
{
    const float* x     = (const float*)d_in[0];
    const int*   ei    = (const int*)d_in[1];
    const int*   batch = (const int*)d_in[2];
    const float* W1    = (const float*)d_in[3];
    const float* b1    = (const float*)d_in[4];
    const float* W2    = (const float*)d_in[5];
    const float* b2    = (const float*)d_in[6];
    const float* eps   = (const float*)d_in[7];
    const float* gamma = (const float*)d_in[8];
    const float* beta  = (const float*)d_in[9];
    float* out = (float*)d_out;

    // ---- workspace layout ----
    // Two H buffers, each [N+1][128] bf16 (row N = dummy zero row)
    unsigned short* Hb  = (unsigned short*)d_ws;              // [N+1,128] bf16
    unsigned short* Hc  = Hb + (size_t)(N_NODES + 1) * D;     // [N+1,128] bf16
    float* stats    = (float*)(Hc + (size_t)(N_NODES + 1) * D); // [3][8][256]
    int*   deg      = (int*)(stats + 3 * 2048);               // [N]
    int*   row_ptr  = deg + N_NODES;                          // [N+1]
    int*   blockSum = row_ptr + N_NODES + 1;                  // [256]
    unsigned short* edge_pos = (unsigned short*)(blockSum + 256);  // [E]
    unsigned short* csr_src  = edge_pos + N_EDGES;            // [E + 7N + 16]
    short* Wt       = (short*)(csr_src + N_EDGES + 7 * N_NODES + 16); // [8][128][128]

    const int* src = ei;
    const int* dst = ei + N_EDGES;

    const int edgeBlocks = (N_EDGES + 255) / 256;      // 3125
    const int scanBlocks = (N_NODES + 255) / 256;      // 196
    const int bnBlocks   = (N_NODES * 16) / 256;       // 3125 exact
    const int gemmBlocks = (N_NODES + 63) / 64;        // 782

    prep_kernel<<<7047, 256, 0, stream>>>(W1, W2, x, Wt, (ushort4*)Hb,
                                          (unsigned*)(Hc + (size_t)N_NODES * D),
                                          deg, stats, out);
    hist_kernel<<<edgeBlocks, 256, 0, stream>>>(dst, deg, edge_pos);
    scan_block_kernel<<<scanBlocks, 256, 0, stream>>>(deg, row_ptr, blockSum);
    scan_fixup_kernel<<<scanBlocks, 256, 0, stream>>>(blockSum, row_ptr, scanBlocks);
    fill_kernel<<<edgeBlocks + scanBlocks, 256, 0, stream>>>(
        src, dst, row_ptr, edge_pos, deg, csr_src);

    unsigned short* Hin  = Hb;
    unsigned short* HoutB = Hc;
    for (int layer = 0; layer < 4; ++layer) {
        const bool bn = (layer < 3);
        if (layer > 0) {
            bnapply_kernel<<<bnBlocks, 256, 0, stream>>>(
                (uint4*)Hin, stats + (size_t)(layer - 1) * 2048,
                gamma + (size_t)(layer - 1) * D, beta + (size_t)(layer - 1) * D);
        }
        layer_kernel<<<gemmBlocks, 256, 0, stream>>>(
            Hin, row_ptr, csr_src, eps + layer,
            Wt + (size_t)layer * 16384, Wt + (size_t)(4 + layer) * 16384,
            b1 + (size_t)layer * D, b2 + (size_t)layer * D, HoutB,
            bn ? stats + (size_t)layer * 2048 : nullptr,
            bn ? nullptr : batch,
            bn ? nullptr : out, N_NODES);
        unsigned short* tmp = Hin; Hin = HoutB; HoutB = tmp;
    }
}